// Round 1
// 1009.034 us; speedup vs baseline: 1.0453x; 1.0453x over previous
//
#include <hip/hip_runtime.h>
#include <stdint.h>

// ---------------------------------------------------------------------------
// ConditionedCTKoopmanTransition: d=512, u=32, n_obs=50, B=512, T=256
// v2 restructure:
//   1. expm via scaling s=2 + degree-7 Paterson-Stockmeyer Taylor (6 GEMMs,
//      was 12). ||A_ct*dt|| <= ~1.43 -> theta <= 0.36, trunc err ~7e-9.
//   2. Recurrence decoupled: boundary-only scan z0_{c+1} = [z0_c|U_c]@Wlast^T
//      (15 tiny sequential GEMMs), then ALL 16 chunks' 512x9216 GEMMs in ONE
//      parallel dispatch (was 16 serialized 512x8192 GEMMs).
//   3. Y fused into the big GEMM: W extended by 1024 rows
//      Wy[(j,o),k] = (C@[A^j | G_{j-i}])[o,k] + delta_{i==j} dt*D[o,u].
//      k_ygemm (and its 268 MB Z re-read) deleted.
// ---------------------------------------------------------------------------

typedef __bf16 bf16x8 __attribute__((ext_vector_type(8)));
typedef float  f32x4  __attribute__((ext_vector_type(4)));

#define NE  576
#define NE3 1728   // 3*NE (split-bf16: [hi|hi|lo] x [hi|lo|hi])

__device__ __forceinline__ unsigned short f2bf(float x){
  union { float f; unsigned int u; } v; v.f = x;
  unsigned int r = (v.u + 0x7fffu + ((v.u >> 16) & 1u)) >> 16;
  return (unsigned short)r;
}
__device__ __forceinline__ float bf2f(unsigned short h){
  union { float f; unsigned int u; } v; v.u = ((unsigned int)h) << 16;
  return v.f;
}

__device__ __forceinline__ void gll16(const void* g, void* l){
  __builtin_amdgcn_global_load_lds((__attribute__((address_space(1))) void*)g,
                                   (__attribute__((address_space(3))) void*)l,
                                   16, 0, 0);
}

// ---------------------------------------------------------------------------
// build scaled augmented matrix X = Maug * dt / 4, f32 + split forms
// ---------------------------------------------------------------------------
__global__ __launch_bounds__(256) void k_build_M(
    const float* __restrict__ skew, const float* __restrict__ gamma,
    const float* __restrict__ dtp, const float* __restrict__ B_ct,
    float* __restrict__ Xf, unsigned short* __restrict__ XAp,
    unsigned short* __restrict__ XBt){
  int id = blockIdx.x * 256 + threadIdx.x;
  if (id >= NE * NE) return;
  int r = id / NE, c = id % NE;
  float sc = dtp[0] * 0.25f;     // s=2 scaling
  float v = 0.f;
  if (r < 512 && c < 512) {
    if (r < c) {
      long k = 511L * r - (long)r * (r - 1) / 2 + (c - r - 1);
      v = skew[k];
    } else if (r > c) {
      long k = 511L * c - (long)c * (c - 1) / 2 + (r - c - 1);
      v = -skew[k];
    } else {
      float g = gamma[r];
      float sp = (g > 20.f) ? g : log1pf(expf(g));
      v = -sp;
    }
  } else if (r < 512 && c >= 512 && c < 544) {
    v = B_ct[r * 32 + (c - 512)];
  }
  v *= sc;
  Xf[id] = v;
  unsigned short hi = f2bf(v);
  unsigned short lo = f2bf(v - bf2f(hi));
  XAp[(long)r * NE3 + c]          = hi;
  XAp[(long)r * NE3 + NE + c]     = hi;
  XAp[(long)r * NE3 + 2 * NE + c] = lo;
  XBt[(long)c * NE3 + r]          = hi;
  XBt[(long)c * NE3 + NE + r]     = lo;
  XBt[(long)c * NE3 + 2 * NE + r] = hi;
}

// ---------------------------------------------------------------------------
// split-bf16 GEMM for expm: C(576x576) = A*B (+Cadd), K=1728 over split forms
// ---------------------------------------------------------------------------
__global__ __launch_bounds__(256) void k_expm_gemm(
    const unsigned short* __restrict__ Ap, const unsigned short* __restrict__ Bt,
    const float* __restrict__ Cadd, float* __restrict__ outF,
    unsigned short* __restrict__ outAp, unsigned short* __restrict__ outBt){
  __shared__ __align__(16) unsigned short As[32 * 32];
  __shared__ __align__(16) unsigned short Bs[32 * 32];
  int tid = threadIdx.x, wave = tid >> 6, lane = tid & 63;
  int wm = wave & 1, wn = wave >> 1;
  int m0 = blockIdx.y * 32, n0 = blockIdx.x * 32;
  int lr = lane & 15, kq = lane >> 4;
  f32x4 acc = {0.f, 0.f, 0.f, 0.f};
  for (int kt = 0; kt < NE3; kt += 32) {
    __syncthreads();
    for (int base = wave * 64; base < 128; base += 256) {
      int cc = base + lane; int rr = cc >> 2, k8 = (cc & 3) << 3;
      gll16(Ap + (long)(m0 + rr) * NE3 + kt + k8, As + base * 8);
    }
    for (int base = (wave ^ 2) * 64; base < 128; base += 256) {
      int cc = base + lane; int rr = cc >> 2, k8 = (cc & 3) << 3;
      gll16(Bt + (long)(n0 + rr) * NE3 + kt + k8, Bs + base * 8);
    }
    __syncthreads();
    bf16x8 af = *(const bf16x8*)&As[(wm * 16 + lr) * 32 + kq * 8];
    bf16x8 bf = *(const bf16x8*)&Bs[(wn * 16 + lr) * 32 + kq * 8];
    acc = __builtin_amdgcn_mfma_f32_16x16x32_bf16(af, bf, acc, 0, 0, 0);
  }
  int n = n0 + wn * 16 + lr;
  for (int i = 0; i < 4; i++) {
    int m = m0 + wm * 16 + kq * 4 + i;
    float v = acc[i];
    if (Cadd) v += Cadd[(long)m * NE + n];
    if (outF) outF[(long)m * NE + n] = v;
    unsigned short hi = f2bf(v);
    unsigned short lo = f2bf(v - bf2f(hi));
    if (outAp) {
      outAp[(long)m * NE3 + n]          = hi;
      outAp[(long)m * NE3 + NE + n]     = hi;
      outAp[(long)m * NE3 + 2 * NE + n] = lo;
    }
    if (outBt) {
      outBt[(long)n * NE3 + m]          = hi;
      outBt[(long)n * NE3 + NE + m]     = lo;
      outBt[(long)n * NE3 + 2 * NE + m] = hi;
    }
  }
}

// ---------------------------------------------------------------------------
// degree-7 PS coefficients: B0 (f32 Cadd), B1 (split Ap).  E = B1*X4 + B0
// ---------------------------------------------------------------------------
__global__ __launch_bounds__(256) void k_poly(
    const float* __restrict__ Xf, const float* __restrict__ X2f,
    const float* __restrict__ X3f, float* __restrict__ B0,
    unsigned short* __restrict__ B1Ap){
  int id = blockIdx.x * 256 + threadIdx.x;
  if (id >= NE * NE) return;
  int r = id / NE, c = id % NE;
  float x = Xf[id], x2 = X2f[id], x3 = X3f[id];
  float ii = (r == c) ? 1.f : 0.f;
  float b0 = ii + x + x2 * 0.5f + x3 * (1.f / 6.f);
  float b1 = ii * (1.f / 24.f) + x * (1.f / 120.f) + x2 * (1.f / 720.f) + x3 * (1.f / 5040.f);
  B0[id] = b0;
  unsigned short hi = f2bf(b1), lo = f2bf(b1 - bf2f(hi));
  B1Ap[(long)r * NE3 + c]          = hi;
  B1Ap[(long)r * NE3 + NE + c]     = hi;
  B1Ap[(long)r * NE3 + 2 * NE + c] = lo;
}

// ---------------------------------------------------------------------------
// extract A_bar/B_bar from expm result; padded C (64 rows) as CA block 0
// ---------------------------------------------------------------------------
__global__ __launch_bounds__(256) void k_extract(
    const float* __restrict__ F, const float* __restrict__ Cin,
    unsigned short* __restrict__ WbigT, unsigned short* __restrict__ PT1,
    unsigned short* __restrict__ BbarT, unsigned short* __restrict__ G0,
    unsigned short* __restrict__ CA0){
  long id = (long)blockIdx.x * 256 + threadIdx.x;
  if (id < 512 * 512) {
    int m = (int)(id >> 9), k = (int)(id & 511);
    WbigT[(long)m * 1024 + k] = f2bf(F[(long)m * NE + k]);   // A^1 row-major
    PT1[id] = f2bf(F[(long)k * NE + m]);                      // (A^1)^T
  }
  if (id < 512 * 32) {
    int dd = (int)(id >> 5), u = (int)(id & 31);
    unsigned short h = f2bf(F[(long)dd * NE + 512 + u]);
    G0[id] = h;                         // B_bar row-major (512x32)
    BbarT[(long)u * 512 + dd] = h;      // B_bar^T (32x512)
  }
  if (id < 64 * 512) {                  // zero-padded C (rows 50..63 = 0)
    CA0[id] = (id < 50 * 512) ? f2bf(Cin[id]) : (unsigned short)0;
  }
}

// ---------------------------------------------------------------------------
// generic bf16 "bt" GEMM: C[m,n] = sum_k A[m,k]*Bt[n,k], bf16 out, batched z
// ---------------------------------------------------------------------------
template<int BM, int BN, int WM, int WN>
__global__ __launch_bounds__(256) void k_btgemm(
    const unsigned short* __restrict__ A, int ldA, long sAz,
    const unsigned short* __restrict__ Bt, int ldB, long sBz,
    unsigned short* __restrict__ C, int ldC, long sCz, int K){
  constexpr int FM = BM / (16 * WM), FN = BN / (16 * WN);
  __shared__ __align__(16) unsigned short As[BM * 32];
  __shared__ __align__(16) unsigned short Bs[BN * 32];
  int tid = threadIdx.x, wave = tid >> 6, lane = tid & 63;
  int wm = wave % WM, wn = wave / WM;
  long z = blockIdx.z;
  const unsigned short* Ab = A + z * sAz;
  const unsigned short* Bb = Bt + z * sBz;
  unsigned short* Cb = C + z * sCz;
  int m0 = blockIdx.y * BM, n0 = blockIdx.x * BN;
  int lr = lane & 15, kq = lane >> 4;
  f32x4 acc[FM][FN];
  f32x4 z4 = {0.f, 0.f, 0.f, 0.f};
  for (int i = 0; i < FM; i++) for (int j = 0; j < FN; j++) acc[i][j] = z4;
  for (int kt = 0; kt < K; kt += 32) {
    __syncthreads();
    for (int base = wave * 64; base < BM * 4; base += 256) {
      int cc = base + lane; int rr = cc >> 2, k8 = (cc & 3) << 3;
      gll16(Ab + (long)(m0 + rr) * ldA + kt + k8, As + base * 8);
    }
    for (int base = (wave ^ 2) * 64; base < BN * 4; base += 256) {
      int cc = base + lane; int rr = cc >> 2, k8 = (cc & 3) << 3;
      gll16(Bb + (long)(n0 + rr) * ldB + kt + k8, Bs + base * 8);
    }
    __syncthreads();
    bf16x8 af[FM], bfr[FN];
    for (int i = 0; i < FM; i++)
      af[i] = *(const bf16x8*)&As[(wm * (16 * FM) + i * 16 + lr) * 32 + kq * 8];
    for (int j = 0; j < FN; j++)
      bfr[j] = *(const bf16x8*)&Bs[(wn * (16 * FN) + j * 16 + lr) * 32 + kq * 8];
    for (int i = 0; i < FM; i++)
      for (int j = 0; j < FN; j++)
        acc[i][j] = __builtin_amdgcn_mfma_f32_16x16x32_bf16(af[i], bfr[j], acc[i][j], 0, 0, 0);
  }
  for (int i = 0; i < FM; i++)
    for (int j = 0; j < FN; j++) {
      int n = n0 + wn * (16 * FN) + j * 16 + lr;
      for (int r = 0; r < 4; r++) {
        int m = m0 + wm * (16 * FM) + i * 16 + kq * 4 + r;
        Cb[(long)m * ldC + n] = f2bf(acc[i][j][r]);
      }
    }
}

// batched 512x512 bf16 transpose: dst(ld512)[m][k] = src(ld1024)[k][m]
__global__ __launch_bounds__(256) void k_transpose512(
    const unsigned short* __restrict__ src, long sSz,
    unsigned short* __restrict__ dst, long sDz){
  long z = blockIdx.z;
  const unsigned short* S = src + z * sSz;
  unsigned short* D = dst + z * sDz;
  int id = blockIdx.x * 256 + threadIdx.x;
  int m = id >> 9, k = id & 511;
  D[(long)m * 512 + k] = S[(long)k * 1024 + m];
}

// fill U-region of WbigT rows 0..8191: WbigT[n][512+32*(i-1)+uu] = G_{j-i}
__global__ __launch_bounds__(256) void k_assembleU(
    const unsigned short* __restrict__ G, unsigned short* __restrict__ WbigT){
  long id = (long)blockIdx.x * 256 + threadIdx.x;   // over 8192*512
  int n = (int)(id >> 9), kk2 = (int)(id & 511);
  int j = (n >> 9) + 1, dcol = n & 511;
  int i = (kk2 >> 5) + 1, uu = kk2 & 31;
  unsigned short v = 0;
  if (i <= j) v = G[(long)(j - i) * 16384 + dcol * 32 + uu];
  WbigT[(long)n * 1024 + 512 + kk2] = v;
}

// fill Y-region of WbigT rows 8192..9215:
// row 8192 + jm1*64 + o: k<512 -> CA_{jm1+1}[o,k];
// k=512+32(i-1)+u -> (i<=j)? CG_{j-i}[o,u] : 0, plus (i==j) dt*D[o,u]
__global__ __launch_bounds__(256) void k_assembleWy(
    const unsigned short* __restrict__ CA, const unsigned short* __restrict__ CG,
    const float* __restrict__ Din, const float* __restrict__ dtp,
    unsigned short* __restrict__ WbigT){
  int id = blockIdx.x * 256 + threadIdx.x;    // over 1024*1024
  int np = id >> 10, kp = id & 1023;
  int jm1 = np >> 6, o = np & 63;
  unsigned short v;
  if (kp < 512) {
    v = CA[(long)(jm1 + 1) * 32768 + o * 512 + kp];
  } else {
    int i = ((kp - 512) >> 5) + 1, u = kp & 31;
    float f = 0.f;
    if (i <= jm1 + 1) f = bf2f(CG[(long)(jm1 + 1 - i) * 2048 + o * 32 + u]);
    if (i == jm1 + 1 && o < 50) f += dtp[0] * Din[o * 32 + u];
    v = f2bf(f);
  }
  WbigT[(long)(8192 + np) * 1024 + kp] = v;
}

// pack Xbuf: [Z0 bf16 (c=0 only) | U bf16 for all chunks]
__global__ __launch_bounds__(256) void k_packX(
    const float* __restrict__ zdyn, const float* __restrict__ U,
    unsigned short* __restrict__ Xbuf){
  long id = (long)blockIdx.x * 256 + threadIdx.x;   // over 16*512*1024
  long c = id >> 19;
  int rem = (int)(id & ((1 << 19) - 1));
  int b = rem >> 10, col = rem & 1023;
  if (col < 512) {
    if (c == 0) Xbuf[id] = f2bf(zdyn[(long)b * 512 + col]);
  } else {
    int kk2 = col - 512;
    int t = (int)(c * 16) + (kk2 >> 5), uu = kk2 & 31;
    Xbuf[id] = f2bf(U[((long)t * 512 + b) * 32 + uu]);
  }
}

// ---------------------------------------------------------------------------
// 128x128 bf16 MFMA GEMM (m97 structure), 2 modes:
//  MODE 0 (scan): out bf16 -> Xnext (z0_{c+1} = [z0_c|U_c] @ Wlast^T), N=512
//  MODE 1 (big):  all 16 chunks batched over blockIdx.z, N=9216:
//                 n<8192 -> Z f32; n>=8192 -> Y f32 (o<50)
// ---------------------------------------------------------------------------
template<int MODE>
__global__ __launch_bounds__(256) void k_mm128(
    const unsigned short* __restrict__ Xall, const unsigned short* __restrict__ W,
    float* __restrict__ Zout, float* __restrict__ Yout,
    unsigned short* __restrict__ Xnext, int c0){
  __shared__ __align__(16) unsigned short As[128 * 32];
  __shared__ __align__(16) unsigned short Bs[128 * 32];
  int tid = threadIdx.x, wave = tid >> 6, lane = tid & 63;
  int wm = wave & 1, wn = wave >> 1;
  int c = (MODE == 1) ? blockIdx.z : c0;
  const unsigned short* Xc = Xall + (long)c * 524288;
  int m0 = blockIdx.y * 128, n0 = blockIdx.x * 128;
  int lr = lane & 15, kq = lane >> 4;
  f32x4 acc[4][4];
  f32x4 z4 = {0.f, 0.f, 0.f, 0.f};
  for (int i = 0; i < 4; i++) for (int j = 0; j < 4; j++) acc[i][j] = z4;
  for (int kt = 0; kt < 1024; kt += 32) {
    __syncthreads();
    for (int s = 0; s < 512; s += 256) {            // A tile: 128x32 = 512 x16B
      int base = wave * 64 + s;
      int cc = base + lane, rr = cc >> 2, k8 = (cc & 3) << 3;
      gll16(Xc + (long)(m0 + rr) * 1024 + kt + k8, As + base * 8);
    }
    for (int s = 0; s < 512; s += 256) {            // B tile: 128x32
      int base = wave * 64 + s;
      int cc = base + lane, rr = cc >> 2, k8 = (cc & 3) << 3;
      gll16(W + (long)(n0 + rr) * 1024 + kt + k8, Bs + base * 8);
    }
    __syncthreads();
    bf16x8 af[4], bfr[4];
    for (int i = 0; i < 4; i++)
      af[i] = *(const bf16x8*)&As[(wm * 64 + i * 16 + lr) * 32 + kq * 8];
    for (int j = 0; j < 4; j++)
      bfr[j] = *(const bf16x8*)&Bs[(wn * 64 + j * 16 + lr) * 32 + kq * 8];
    for (int i = 0; i < 4; i++)
      for (int j = 0; j < 4; j++)
        acc[i][j] = __builtin_amdgcn_mfma_f32_16x16x32_bf16(af[i], bfr[j], acc[i][j], 0, 0, 0);
  }
  if (MODE == 0) {
    for (int j = 0; j < 4; j++) {
      int n = n0 + wn * 64 + j * 16 + lr;
      for (int i = 0; i < 4; i++)
        for (int r = 0; r < 4; r++) {
          int m = m0 + wm * 64 + i * 16 + kq * 4 + r;
          Xnext[(long)m * 1024 + n] = f2bf(acc[i][j][r]);
        }
    }
  } else {
    int t0 = c * 16;
    if (n0 < 8192) {
      int jm1 = n0 >> 9;              // block never crosses a 512 boundary
      float* Zt = Zout + (long)(t0 + jm1) * 262144;
      for (int j = 0; j < 4; j++) {
        int n = n0 + wn * 64 + j * 16 + lr, dcol = n & 511;
        for (int i = 0; i < 4; i++)
          for (int r = 0; r < 4; r++) {
            int m = m0 + wm * 64 + i * 16 + kq * 4 + r;
            Zt[(long)m * 512 + dcol] = acc[i][j][r];
          }
      }
    } else {
      for (int j = 0; j < 4; j++) {
        int n = n0 + wn * 64 + j * 16 + lr;
        int q = n - 8192, jm1 = q >> 6, o = q & 63;
        if (o >= 50) continue;
        int t = t0 + jm1;
        for (int i = 0; i < 4; i++)
          for (int r = 0; r < 4; r++) {
            int m = m0 + wm * 64 + i * 16 + kq * 4 + r;
            Yout[((long)t * 512 + m) * 50 + o] = acc[i][j][r];
          }
      }
    }
  }
}

// ---------------------------------------------------------------------------
// workspace layout (bytes)
// ---------------------------------------------------------------------------
static constexpr long NE2F = 331776L * 4;   // 576^2 f32      = 1,327,104
static constexpr long SPLT = 995328L * 2;   // 576*1728 bf16  = 1,990,656
// region A (expm scratch; only FF is read after the expm chain)
static constexpr long OFF_XF   = 0;
static constexpr long OFF_X2F  = OFF_XF   + NE2F;
static constexpr long OFF_X3F  = OFF_X2F  + NE2F;
static constexpr long OFF_B0F  = OFF_X3F  + NE2F;
static constexpr long OFF_XAP  = OFF_B0F  + NE2F;    //  5,308,416
static constexpr long OFF_XBT  = OFF_XAP  + SPLT;
static constexpr long OFF_X2AP = OFF_XBT  + SPLT;
static constexpr long OFF_X2BT = OFF_X2AP + SPLT;
static constexpr long OFF_X4BT = OFF_X2BT + SPLT;
static constexpr long OFF_B1AP = OFF_X4BT + SPLT;
static constexpr long OFF_EAP  = OFF_B1AP + SPLT;
static constexpr long OFF_EBT  = OFF_EAP  + SPLT;
static constexpr long OFF_FAP  = OFF_EBT  + SPLT;
static constexpr long OFF_FBT  = OFF_FAP  + SPLT;
static constexpr long OFF_FF   = OFF_FBT  + SPLT;    // 25,214,976 .. 26,542,080
// region B aliases region A; all prep writes stay below OFF_FF until k_packX
static constexpr long OFF_WBT  = 0;                            // 9216x1024 bf16 = 18,874,368
static constexpr long OFF_PT   = 18874368;                     // 8 * 512x512 bf16 = 4 MB
static constexpr long OFF_BBT  = OFF_PT  + 8L * 262144 * 2;    // 23,068,672
static constexpr long OFF_G    = OFF_BBT + 32768;              // 23,101,440 (16 x 512x32)
static constexpr long OFF_CA   = OFF_G   + 16L * 16384 * 2;    // 23,625,728 (17 x 64x512)
static constexpr long OFF_CG   = OFF_CA  + 17L * 32768 * 2;    // 24,739,840 (16 x 64x32)
// Xb overwrites PT/BbarT/G/CA/CG (all dead by k_packX time); ends 35,651,584
static constexpr long OFF_XB   = OFF_PT;

extern "C" void kernel_launch(void* const* d_in, const int* in_sizes, int n_in,
                              void* d_out, int out_size, void* d_ws, size_t ws_size,
                              hipStream_t stream){
  const float* z_dyn = (const float*)d_in[0];
  const float* dtp   = (const float*)d_in[2];
  const float* U     = (const float*)d_in[3];
  const float* skew  = (const float*)d_in[4];
  const float* gamma = (const float*)d_in[5];
  const float* B_ct  = (const float*)d_in[6];
  const float* Cin   = (const float*)d_in[7];
  const float* Din   = (const float*)d_in[8];
  float* Zout = (float*)d_out;
  float* Yout = Zout + 67108864L;   // 256*512*512

  char* ws = (char*)d_ws;
  float* Xf  = (float*)(ws + OFF_XF);
  float* X2f = (float*)(ws + OFF_X2F);
  float* X3f = (float*)(ws + OFF_X3F);
  float* B0f = (float*)(ws + OFF_B0F);
  float* Ff  = (float*)(ws + OFF_FF);
  unsigned short* XAp  = (unsigned short*)(ws + OFF_XAP);
  unsigned short* XBt  = (unsigned short*)(ws + OFF_XBT);
  unsigned short* X2Ap = (unsigned short*)(ws + OFF_X2AP);
  unsigned short* X2Bt = (unsigned short*)(ws + OFF_X2BT);
  unsigned short* X4Bt = (unsigned short*)(ws + OFF_X4BT);
  unsigned short* B1Ap = (unsigned short*)(ws + OFF_B1AP);
  unsigned short* EAp  = (unsigned short*)(ws + OFF_EAP);
  unsigned short* EBt  = (unsigned short*)(ws + OFF_EBT);
  unsigned short* FAp  = (unsigned short*)(ws + OFF_FAP);
  unsigned short* FBt  = (unsigned short*)(ws + OFF_FBT);
  unsigned short* WbigT = (unsigned short*)(ws + OFF_WBT);
  unsigned short* PT    = (unsigned short*)(ws + OFF_PT);
  unsigned short* BbarT = (unsigned short*)(ws + OFF_BBT);
  unsigned short* Gar   = (unsigned short*)(ws + OFF_G);
  unsigned short* CAb   = (unsigned short*)(ws + OFF_CA);
  unsigned short* CGb   = (unsigned short*)(ws + OFF_CG);
  unsigned short* Xb    = (unsigned short*)(ws + OFF_XB);

  dim3 b256(256);
  dim3 gE(18, 18);
  const long WBLK = 524288;  // 512*1024 elements
  const long PBLK = 262144;  // 512*512 elements

  // ---- expm(Maug*dt): scaling s=2 + degree-7 PS Taylor (6 GEMMs) ----
  k_build_M<<<dim3(1296), b256, 0, stream>>>(skew, gamma, dtp, B_ct, Xf, XAp, XBt);
  k_expm_gemm<<<gE, b256, 0, stream>>>(XAp,  XBt,  nullptr, X2f, X2Ap, X2Bt);      // X2
  k_expm_gemm<<<gE, b256, 0, stream>>>(X2Ap, XBt,  nullptr, X3f, nullptr, nullptr); // X3
  k_expm_gemm<<<gE, b256, 0, stream>>>(X2Ap, X2Bt, nullptr, nullptr, nullptr, X4Bt);// X4
  k_poly<<<dim3(1296), b256, 0, stream>>>(Xf, X2f, X3f, B0f, B1Ap);
  k_expm_gemm<<<gE, b256, 0, stream>>>(B1Ap, X4Bt, B0f, nullptr, EAp, EBt);        // E = B1*X4+B0
  k_expm_gemm<<<gE, b256, 0, stream>>>(EAp, EBt, nullptr, nullptr, FAp, FBt);      // F = E^2
  k_expm_gemm<<<gE, b256, 0, stream>>>(FAp, FBt, nullptr, Ff, nullptr, nullptr);   // Ff = F^2

  // ---- extract A_bar/B_bar, padded C ----
  k_extract<<<dim3(1024), b256, 0, stream>>>(Ff, Cin, WbigT, PT, BbarT, Gar, CAb);

  // ---- powers of A by doubling: Apow_j = WbigT block j-1 (ld 1024) ----
  k_btgemm<64,64,2,2><<<dim3(8,8,1), b256, 0, stream>>>(WbigT, 1024, 0, PT, 512, 0, WbigT + WBLK, 1024, 0, 512);               // A2
  k_transpose512<<<dim3(1024,1,1), b256, 0, stream>>>(WbigT + WBLK, WBLK, PT + PBLK, PBLK);                                     // PT2
  k_btgemm<64,64,2,2><<<dim3(8,8,2), b256, 0, stream>>>(WbigT + WBLK, 1024, 0, PT, 512, PBLK, WbigT + 2*WBLK, 1024, WBLK, 512); // A3,4
  k_transpose512<<<dim3(1024,1,2), b256, 0, stream>>>(WbigT + 2*WBLK, WBLK, PT + 2*PBLK, PBLK);                                 // PT3,4
  k_btgemm<64,64,2,2><<<dim3(8,8,4), b256, 0, stream>>>(WbigT + 3*WBLK, 1024, 0, PT, 512, PBLK, WbigT + 4*WBLK, 1024, WBLK, 512);// A5..8
  k_transpose512<<<dim3(1024,1,4), b256, 0, stream>>>(WbigT + 4*WBLK, WBLK, PT + 4*PBLK, PBLK);                                 // PT5..8
  k_btgemm<64,64,2,2><<<dim3(8,8,8), b256, 0, stream>>>(WbigT + 7*WBLK, 1024, 0, PT, 512, PBLK, WbigT + 8*WBLK, 1024, WBLK, 512);// A9..16
  // G_k = Apow_k * B_bar (k=1..15); G_0 from extract
  k_btgemm<64,32,4,1><<<dim3(1,8,15), b256, 0, stream>>>(WbigT, 1024, WBLK, BbarT, 512, 0, Gar + 16384, 32, 16384, 512);

  // ---- CA_m = C@A^m (m=1..16), CG_m = CA_m@B_bar (m=0..15) for Y fusion ----
  k_btgemm<64,64,2,2><<<dim3(8,1,8), b256, 0, stream>>>(CAb, 512, 0, PT, 512, PBLK, CAb + 32768, 512, 32768, 512);             // CA1..8
  k_btgemm<64,64,2,2><<<dim3(8,1,8), b256, 0, stream>>>(CAb + 32768, 512, 32768, PT + 7*PBLK, 512, 0, CAb + 9L*32768, 512, 32768, 512); // CA9..16
  k_btgemm<64,32,4,1><<<dim3(1,1,16), b256, 0, stream>>>(CAb, 512, 32768, BbarT, 512, 0, CGb, 32, 2048, 512);                  // CG0..15

  // ---- assemble W (U-region + Y-region), pack X buffers ----
  k_assembleU<<<dim3(16384), b256, 0, stream>>>(Gar, WbigT);
  k_assembleWy<<<dim3(4096), b256, 0, stream>>>(CAb, CGb, Din, dtp, WbigT);
  k_packX<<<dim3(32768), b256, 0, stream>>>(z_dyn, U, Xb);

  // ---- boundary-only scan: z0_{c+1} = [z0_c|U_c] @ Wlast^T (bf16) ----
  for (int c = 0; c < 15; c++) {
    k_mm128<0><<<dim3(4, 4, 1), b256, 0, stream>>>(
        Xb, WbigT + 15L * WBLK, nullptr, nullptr, Xb + (long)(c + 1) * WBLK, c);
  }

  // ---- ONE parallel dispatch: all 16 chunks, Z (n<8192) + Y (n>=8192) ----
  k_mm128<1><<<dim3(72, 4, 16), b256, 0, stream>>>(Xb, WbigT, Zout, Yout, nullptr, 0);
}

// Round 2
// 794.262 us; speedup vs baseline: 1.3279x; 1.2704x over previous
//
#include <hip/hip_runtime.h>
#include <stdint.h>

// ---------------------------------------------------------------------------
// ConditionedCTKoopmanTransition: d=512, u=32, n_obs=50, B=512, T=256
// v3:
//   1. Boundary recurrence z0_{c+1} = z0_c@A16^T + U_c@GU^T computed by
//      parallel prefix (Hillis-Steele, 4 rounds, ping-pong, f32 carry)
//      instead of 15 serial latency-bound GEMM launches.
//   2. BK=64 in all MFMA kernels (half the barrier/drain iterations).
//   3. Scratch for prefix lives in d_out (dead before the big GEMM
//      overwrites every element of Z and Y).
// ---------------------------------------------------------------------------

typedef __bf16 bf16x8 __attribute__((ext_vector_type(8)));
typedef float  f32x4  __attribute__((ext_vector_type(4)));

#define NE  576
#define NE3 1728   // 3*NE (split-bf16: [hi|hi|lo] x [hi|lo|hi])

__device__ __forceinline__ unsigned short f2bf(float x){
  union { float f; unsigned int u; } v; v.f = x;
  unsigned int r = (v.u + 0x7fffu + ((v.u >> 16) & 1u)) >> 16;
  return (unsigned short)r;
}
__device__ __forceinline__ float bf2f(unsigned short h){
  union { float f; unsigned int u; } v; v.u = ((unsigned int)h) << 16;
  return v.f;
}

__device__ __forceinline__ void gll16(const void* g, void* l){
  __builtin_amdgcn_global_load_lds((__attribute__((address_space(1))) void*)g,
                                   (__attribute__((address_space(3))) void*)l,
                                   16, 0, 0);
}

// ---------------------------------------------------------------------------
// build scaled augmented matrix X = Maug * dt / 4, f32 + split forms
// ---------------------------------------------------------------------------
__global__ __launch_bounds__(256) void k_build_M(
    const float* __restrict__ skew, const float* __restrict__ gamma,
    const float* __restrict__ dtp, const float* __restrict__ B_ct,
    float* __restrict__ Xf, unsigned short* __restrict__ XAp,
    unsigned short* __restrict__ XBt){
  int id = blockIdx.x * 256 + threadIdx.x;
  if (id >= NE * NE) return;
  int r = id / NE, c = id % NE;
  float sc = dtp[0] * 0.25f;     // s=2 scaling
  float v = 0.f;
  if (r < 512 && c < 512) {
    if (r < c) {
      long k = 511L * r - (long)r * (r - 1) / 2 + (c - r - 1);
      v = skew[k];
    } else if (r > c) {
      long k = 511L * c - (long)c * (c - 1) / 2 + (r - c - 1);
      v = -skew[k];
    } else {
      float g = gamma[r];
      float sp = (g > 20.f) ? g : log1pf(expf(g));
      v = -sp;
    }
  } else if (r < 512 && c >= 512 && c < 544) {
    v = B_ct[r * 32 + (c - 512)];
  }
  v *= sc;
  Xf[id] = v;
  unsigned short hi = f2bf(v);
  unsigned short lo = f2bf(v - bf2f(hi));
  XAp[(long)r * NE3 + c]          = hi;
  XAp[(long)r * NE3 + NE + c]     = hi;
  XAp[(long)r * NE3 + 2 * NE + c] = lo;
  XBt[(long)c * NE3 + r]          = hi;
  XBt[(long)c * NE3 + NE + r]     = lo;
  XBt[(long)c * NE3 + 2 * NE + r] = hi;
}

// ---------------------------------------------------------------------------
// split-bf16 GEMM for expm: C(576x576) = A*B (+Cadd), K=1728, BK=64
// ---------------------------------------------------------------------------
__global__ __launch_bounds__(256) void k_expm_gemm(
    const unsigned short* __restrict__ Ap, const unsigned short* __restrict__ Bt,
    const float* __restrict__ Cadd, float* __restrict__ outF,
    unsigned short* __restrict__ outAp, unsigned short* __restrict__ outBt){
  __shared__ __align__(16) unsigned short As[32 * 64];
  __shared__ __align__(16) unsigned short Bs[32 * 64];
  int tid = threadIdx.x, wave = tid >> 6, lane = tid & 63;
  int wm = wave & 1, wn = wave >> 1;
  int m0 = blockIdx.y * 32, n0 = blockIdx.x * 32;
  int lr = lane & 15, kq = lane >> 4;
  f32x4 acc = {0.f, 0.f, 0.f, 0.f};
  for (int kt = 0; kt < NE3; kt += 64) {
    __syncthreads();
    {
      int base = wave * 64;
      int cc = base + lane; int rr = cc >> 3, k8 = (cc & 7) << 3;
      gll16(Ap + (long)(m0 + rr) * NE3 + kt + k8, As + base * 8);
      gll16(Bt + (long)(n0 + rr) * NE3 + kt + k8, Bs + base * 8);
    }
    __syncthreads();
    for (int h = 0; h < 2; h++) {
      bf16x8 af = *(const bf16x8*)&As[(wm * 16 + lr) * 64 + h * 32 + kq * 8];
      bf16x8 bf = *(const bf16x8*)&Bs[(wn * 16 + lr) * 64 + h * 32 + kq * 8];
      acc = __builtin_amdgcn_mfma_f32_16x16x32_bf16(af, bf, acc, 0, 0, 0);
    }
  }
  int n = n0 + wn * 16 + lr;
  for (int i = 0; i < 4; i++) {
    int m = m0 + wm * 16 + kq * 4 + i;
    float v = acc[i];
    if (Cadd) v += Cadd[(long)m * NE + n];
    if (outF) outF[(long)m * NE + n] = v;
    unsigned short hi = f2bf(v);
    unsigned short lo = f2bf(v - bf2f(hi));
    if (outAp) {
      outAp[(long)m * NE3 + n]          = hi;
      outAp[(long)m * NE3 + NE + n]     = hi;
      outAp[(long)m * NE3 + 2 * NE + n] = lo;
    }
    if (outBt) {
      outBt[(long)n * NE3 + m]          = hi;
      outBt[(long)n * NE3 + NE + m]     = lo;
      outBt[(long)n * NE3 + 2 * NE + m] = hi;
    }
  }
}

// ---------------------------------------------------------------------------
// degree-7 PS coefficients: B0 (f32 Cadd), B1 (split Ap).  E = B1*X4 + B0
// ---------------------------------------------------------------------------
__global__ __launch_bounds__(256) void k_poly(
    const float* __restrict__ Xf, const float* __restrict__ X2f,
    const float* __restrict__ X3f, float* __restrict__ B0,
    unsigned short* __restrict__ B1Ap){
  int id = blockIdx.x * 256 + threadIdx.x;
  if (id >= NE * NE) return;
  int r = id / NE, c = id % NE;
  float x = Xf[id], x2 = X2f[id], x3 = X3f[id];
  float ii = (r == c) ? 1.f : 0.f;
  float b0 = ii + x + x2 * 0.5f + x3 * (1.f / 6.f);
  float b1 = ii * (1.f / 24.f) + x * (1.f / 120.f) + x2 * (1.f / 720.f) + x3 * (1.f / 5040.f);
  B0[id] = b0;
  unsigned short hi = f2bf(b1), lo = f2bf(b1 - bf2f(hi));
  B1Ap[(long)r * NE3 + c]          = hi;
  B1Ap[(long)r * NE3 + NE + c]     = hi;
  B1Ap[(long)r * NE3 + 2 * NE + c] = lo;
}

// ---------------------------------------------------------------------------
// extract A_bar/B_bar from expm result; padded C (64 rows) as CA block 0
// ---------------------------------------------------------------------------
__global__ __launch_bounds__(256) void k_extract(
    const float* __restrict__ F, const float* __restrict__ Cin,
    unsigned short* __restrict__ WbigT, unsigned short* __restrict__ PT1,
    unsigned short* __restrict__ BbarT, unsigned short* __restrict__ G0,
    unsigned short* __restrict__ CA0){
  long id = (long)blockIdx.x * 256 + threadIdx.x;
  if (id < 512 * 512) {
    int m = (int)(id >> 9), k = (int)(id & 511);
    WbigT[(long)m * 1024 + k] = f2bf(F[(long)m * NE + k]);   // A^1 row-major
    PT1[id] = f2bf(F[(long)k * NE + m]);                      // (A^1)^T
  }
  if (id < 512 * 32) {
    int dd = (int)(id >> 5), u = (int)(id & 31);
    unsigned short h = f2bf(F[(long)dd * NE + 512 + u]);
    G0[id] = h;                         // B_bar row-major (512x32)
    BbarT[(long)u * 512 + dd] = h;      // B_bar^T (32x512)
  }
  if (id < 64 * 512) {                  // zero-padded C (rows 50..63 = 0)
    CA0[id] = (id < 50 * 512) ? f2bf(Cin[id]) : (unsigned short)0;
  }
}

// ---------------------------------------------------------------------------
// generic bf16 "bt" GEMM, BK=64: C[m,n] = sum_k A[m,k]*Bt[n,k]
// optional f32 copy of the result (outF). batched over blockIdx.z.
// ---------------------------------------------------------------------------
template<int BM, int BN, int WM, int WN>
__global__ __launch_bounds__(256) void k_btgemm(
    const unsigned short* __restrict__ A, int ldA, long sAz,
    const unsigned short* __restrict__ Bt, int ldB, long sBz,
    unsigned short* __restrict__ C, int ldC, long sCz, int K,
    float* __restrict__ outF, int ldF, long sFz){
  constexpr int FM = BM / (16 * WM), FN = BN / (16 * WN);
  __shared__ __align__(16) unsigned short As[BM * 64];
  __shared__ __align__(16) unsigned short Bs[BN * 64];
  int tid = threadIdx.x, wave = tid >> 6, lane = tid & 63;
  int wm = wave % WM, wn = wave / WM;
  long z = blockIdx.z;
  const unsigned short* Ab = A + z * sAz;
  const unsigned short* Bb = Bt + z * sBz;
  unsigned short* Cb = C + z * sCz;
  float* Fb = outF ? (outF + z * sFz) : nullptr;
  int m0 = blockIdx.y * BM, n0 = blockIdx.x * BN;
  int lr = lane & 15, kq = lane >> 4;
  f32x4 acc[FM][FN];
  f32x4 z4 = {0.f, 0.f, 0.f, 0.f};
  for (int i = 0; i < FM; i++) for (int j = 0; j < FN; j++) acc[i][j] = z4;
  for (int kt = 0; kt < K; kt += 64) {
    __syncthreads();
    for (int base = wave * 64; base < BM * 8; base += 256) {
      int cc = base + lane; int rr = cc >> 3, k8 = (cc & 7) << 3;
      gll16(Ab + (long)(m0 + rr) * ldA + kt + k8, As + base * 8);
    }
    for (int base = wave * 64; base < BN * 8; base += 256) {
      int cc = base + lane; int rr = cc >> 3, k8 = (cc & 7) << 3;
      gll16(Bb + (long)(n0 + rr) * ldB + kt + k8, Bs + base * 8);
    }
    __syncthreads();
    for (int h = 0; h < 2; h++) {
      bf16x8 af[FM], bfr[FN];
      for (int i = 0; i < FM; i++)
        af[i] = *(const bf16x8*)&As[(wm * (16 * FM) + i * 16 + lr) * 64 + h * 32 + kq * 8];
      for (int j = 0; j < FN; j++)
        bfr[j] = *(const bf16x8*)&Bs[(wn * (16 * FN) + j * 16 + lr) * 64 + h * 32 + kq * 8];
      for (int i = 0; i < FM; i++)
        for (int j = 0; j < FN; j++)
          acc[i][j] = __builtin_amdgcn_mfma_f32_16x16x32_bf16(af[i], bfr[j], acc[i][j], 0, 0, 0);
    }
  }
  for (int i = 0; i < FM; i++)
    for (int j = 0; j < FN; j++) {
      int n = n0 + wn * (16 * FN) + j * 16 + lr;
      for (int r = 0; r < 4; r++) {
        int m = m0 + wm * (16 * FM) + i * 16 + kq * 4 + r;
        float v = acc[i][j][r];
        Cb[(long)m * ldC + n] = f2bf(v);
        if (Fb) Fb[(long)m * ldF + n] = v;
      }
    }
}

// batched 512x512 bf16 transpose: dst(ld512)[m][k] = src(ld1024)[k][m]
__global__ __launch_bounds__(256) void k_transpose512(
    const unsigned short* __restrict__ src, long sSz,
    unsigned short* __restrict__ dst, long sDz){
  long z = blockIdx.z;
  const unsigned short* S = src + z * sSz;
  unsigned short* D = dst + z * sDz;
  int id = blockIdx.x * 256 + threadIdx.x;
  int m = id >> 9, k = id & 511;
  D[(long)m * 512 + k] = S[(long)k * 1024 + m];
}

// fill U-region of WbigT rows 0..8191: WbigT[n][512+32*(i-1)+uu] = G_{j-i}
__global__ __launch_bounds__(256) void k_assembleU(
    const unsigned short* __restrict__ G, unsigned short* __restrict__ WbigT){
  long id = (long)blockIdx.x * 256 + threadIdx.x;   // over 8192*512
  int n = (int)(id >> 9), kk2 = (int)(id & 511);
  int j = (n >> 9) + 1, dcol = n & 511;
  int i = (kk2 >> 5) + 1, uu = kk2 & 31;
  unsigned short v = 0;
  if (i <= j) v = G[(long)(j - i) * 16384 + dcol * 32 + uu];
  WbigT[(long)n * 1024 + 512 + kk2] = v;
}

// fill Y-region of WbigT rows 8192..9215
__global__ __launch_bounds__(256) void k_assembleWy(
    const unsigned short* __restrict__ CA, const unsigned short* __restrict__ CG,
    const float* __restrict__ Din, const float* __restrict__ dtp,
    unsigned short* __restrict__ WbigT){
  int id = blockIdx.x * 256 + threadIdx.x;    // over 1024*1024
  int np = id >> 10, kp = id & 1023;
  int jm1 = np >> 6, o = np & 63;
  unsigned short v;
  if (kp < 512) {
    v = CA[(long)(jm1 + 1) * 32768 + o * 512 + kp];
  } else {
    int i = ((kp - 512) >> 5) + 1, u = kp & 31;
    float f = 0.f;
    if (i <= jm1 + 1) f = bf2f(CG[(long)(jm1 + 1 - i) * 2048 + o * 32 + u]);
    if (i == jm1 + 1 && o < 50) f += dtp[0] * Din[o * 32 + u];
    v = f2bf(f);
  }
  WbigT[(long)(8192 + np) * 1024 + kp] = v;
}

// pack Xbuf: [Z0 bf16 (c=0 only) | U bf16 for all chunks]; also f32 z0 copy
__global__ __launch_bounds__(256) void k_packX(
    const float* __restrict__ zdyn, const float* __restrict__ U,
    unsigned short* __restrict__ Xbuf, float* __restrict__ S32a0){
  long id = (long)blockIdx.x * 256 + threadIdx.x;   // over 16*512*1024
  long c = id >> 19;
  int rem = (int)(id & ((1 << 19) - 1));
  int b = rem >> 10, col = rem & 1023;
  if (col < 512) {
    if (c == 0) {
      float zv = zdyn[(long)b * 512 + col];
      Xbuf[id] = f2bf(zv);
      S32a0[(long)b * 512 + col] = zv;
    }
  } else {
    int kk2 = col - 512;
    int t = (int)(c * 16) + (kk2 >> 5), uu = kk2 & 31;
    Xbuf[id] = f2bf(U[((long)t * 512 + b) * 32 + uu]);
  }
}

// ---------------------------------------------------------------------------
// Hillis-Steele prefix round over 16 boundary states (batch = c):
//  c >= h : out[c] = Add32[c] + SinB[c-h] @ R^T   (f32 carry + bf16 copy)
//  c <  h : out[c] = Add32[c]                      (pass-through)
// ---------------------------------------------------------------------------
__global__ __launch_bounds__(256) void k_scanround(
    const unsigned short* __restrict__ SinB, int ldSB, long sSB,
    const float* __restrict__ Add32,
    const unsigned short* __restrict__ R, int ldR,
    float* __restrict__ Out32, unsigned short* __restrict__ OutB,
    int ldOB, long sOB, int h){
  __shared__ __align__(16) unsigned short As[64 * 64];
  __shared__ __align__(16) unsigned short Bs[64 * 64];
  int tid = threadIdx.x, wave = tid >> 6, lane = tid & 63;
  int wm = wave & 1, wn = wave >> 1;
  int c = blockIdx.z;
  int m0 = blockIdx.y * 64, n0 = blockIdx.x * 64;
  int lr = lane & 15, kq = lane >> 4;
  f32x4 acc[2][2];
  f32x4 z4 = {0.f, 0.f, 0.f, 0.f};
  for (int i = 0; i < 2; i++) for (int j = 0; j < 2; j++) acc[i][j] = z4;
  if (c >= h) {
    const unsigned short* Ab = SinB + (long)(c - h) * sSB;
    for (int kt = 0; kt < 512; kt += 64) {
      __syncthreads();
      for (int base = wave * 64; base < 512; base += 256) {
        int cc = base + lane; int rr = cc >> 3, k8 = (cc & 7) << 3;
        gll16(Ab + (long)(m0 + rr) * ldSB + kt + k8, As + base * 8);
      }
      for (int base = wave * 64; base < 512; base += 256) {
        int cc = base + lane; int rr = cc >> 3, k8 = (cc & 7) << 3;
        gll16(R + (long)(n0 + rr) * ldR + kt + k8, Bs + base * 8);
      }
      __syncthreads();
      for (int h2 = 0; h2 < 2; h2++) {
        bf16x8 af[2], bfr[2];
        for (int i = 0; i < 2; i++)
          af[i] = *(const bf16x8*)&As[(wm * 32 + i * 16 + lr) * 64 + h2 * 32 + kq * 8];
        for (int j = 0; j < 2; j++)
          bfr[j] = *(const bf16x8*)&Bs[(wn * 32 + j * 16 + lr) * 64 + h2 * 32 + kq * 8];
        for (int i = 0; i < 2; i++)
          for (int j = 0; j < 2; j++)
            acc[i][j] = __builtin_amdgcn_mfma_f32_16x16x32_bf16(af[i], bfr[j], acc[i][j], 0, 0, 0);
      }
    }
  }
  const float* Ac = Add32 + (long)c * 262144;
  float* O32 = Out32 + (long)c * 262144;
  unsigned short* OB = OutB + (long)c * sOB;
  for (int j = 0; j < 2; j++) {
    int n = n0 + wn * 32 + j * 16 + lr;
    for (int i = 0; i < 2; i++)
      for (int r = 0; r < 4; r++) {
        int m = m0 + wm * 32 + i * 16 + kq * 4 + r;
        float v = acc[i][j][r] + Ac[(long)m * 512 + n];
        O32[(long)m * 512 + n] = v;
        OB[(long)m * ldOB + n] = f2bf(v);
      }
  }
}

// ---------------------------------------------------------------------------
// big fused GEMM: all 16 chunks, [z0_c|U_c](512x1024) @ W^T(1024x9216)
//  n<8192 -> Z f32; n>=8192 -> Y f32 (o<50).  BK=64.
// ---------------------------------------------------------------------------
__global__ __launch_bounds__(256) void k_mmbig(
    const unsigned short* __restrict__ Xall, const unsigned short* __restrict__ W,
    float* __restrict__ Zout, float* __restrict__ Yout){
  __shared__ __align__(16) unsigned short As[128 * 64];
  __shared__ __align__(16) unsigned short Bs[128 * 64];
  int tid = threadIdx.x, wave = tid >> 6, lane = tid & 63;
  int wm = wave & 1, wn = wave >> 1;
  int c = blockIdx.z;
  const unsigned short* Xc = Xall + (long)c * 524288;
  int m0 = blockIdx.y * 128, n0 = blockIdx.x * 128;
  int lr = lane & 15, kq = lane >> 4;
  f32x4 acc[4][4];
  f32x4 z4 = {0.f, 0.f, 0.f, 0.f};
  for (int i = 0; i < 4; i++) for (int j = 0; j < 4; j++) acc[i][j] = z4;
  for (int kt = 0; kt < 1024; kt += 64) {
    __syncthreads();
    for (int base = wave * 64; base < 1024; base += 256) {
      int cc = base + lane; int rr = cc >> 3, k8 = (cc & 7) << 3;
      gll16(Xc + (long)(m0 + rr) * 1024 + kt + k8, As + base * 8);
    }
    for (int base = wave * 64; base < 1024; base += 256) {
      int cc = base + lane; int rr = cc >> 3, k8 = (cc & 7) << 3;
      gll16(W + (long)(n0 + rr) * 1024 + kt + k8, Bs + base * 8);
    }
    __syncthreads();
    for (int h = 0; h < 2; h++) {
      bf16x8 af[4], bfr[4];
      for (int i = 0; i < 4; i++)
        af[i] = *(const bf16x8*)&As[(wm * 64 + i * 16 + lr) * 64 + h * 32 + kq * 8];
      for (int j = 0; j < 4; j++)
        bfr[j] = *(const bf16x8*)&Bs[(wn * 64 + j * 16 + lr) * 64 + h * 32 + kq * 8];
      for (int i = 0; i < 4; i++)
        for (int j = 0; j < 4; j++)
          acc[i][j] = __builtin_amdgcn_mfma_f32_16x16x32_bf16(af[i], bfr[j], acc[i][j], 0, 0, 0);
    }
  }
  int t0 = c * 16;
  if (n0 < 8192) {
    int jm1 = n0 >> 9;              // block never crosses a 512 boundary
    float* Zt = Zout + (long)(t0 + jm1) * 262144;
    for (int j = 0; j < 4; j++) {
      int n = n0 + wn * 64 + j * 16 + lr, dcol = n & 511;
      for (int i = 0; i < 4; i++)
        for (int r = 0; r < 4; r++) {
          int m = m0 + wm * 64 + i * 16 + kq * 4 + r;
          Zt[(long)m * 512 + dcol] = acc[i][j][r];
        }
    }
  } else {
    for (int j = 0; j < 4; j++) {
      int n = n0 + wn * 64 + j * 16 + lr;
      int q = n - 8192, jm1 = q >> 6, o = q & 63;
      if (o >= 50) continue;
      int t = t0 + jm1;
      for (int i = 0; i < 4; i++)
        for (int r = 0; r < 4; r++) {
          int m = m0 + wm * 64 + i * 16 + kq * 4 + r;
          Yout[((long)t * 512 + m) * 50 + o] = acc[i][j][r];
        }
    }
  }
}

// ---------------------------------------------------------------------------
// workspace layout (bytes)
// ---------------------------------------------------------------------------
static constexpr long NE2F = 331776L * 4;   // 576^2 f32      = 1,327,104
static constexpr long SPLT = 995328L * 2;   // 576*1728 bf16  = 1,990,656
// region A (expm scratch; only FF is read after the expm chain)
static constexpr long OFF_XF   = 0;
static constexpr long OFF_X2F  = OFF_XF   + NE2F;
static constexpr long OFF_X3F  = OFF_X2F  + NE2F;
static constexpr long OFF_B0F  = OFF_X3F  + NE2F;
static constexpr long OFF_XAP  = OFF_B0F  + NE2F;
static constexpr long OFF_XBT  = OFF_XAP  + SPLT;
static constexpr long OFF_X2AP = OFF_XBT  + SPLT;
static constexpr long OFF_X2BT = OFF_X2AP + SPLT;
static constexpr long OFF_X4BT = OFF_X2BT + SPLT;
static constexpr long OFF_B1AP = OFF_X4BT + SPLT;
static constexpr long OFF_EAP  = OFF_B1AP + SPLT;
static constexpr long OFF_EBT  = OFF_EAP  + SPLT;
static constexpr long OFF_FAP  = OFF_EBT  + SPLT;
static constexpr long OFF_FBT  = OFF_FAP  + SPLT;
static constexpr long OFF_FF   = OFF_FBT  + SPLT;
// region B aliases region A; all prep writes stay below OFF_FF until k_packX
static constexpr long OFF_WBT  = 0;                            // 9216x1024 bf16 = 18,874,368
static constexpr long OFF_PT   = 18874368;                     // 8 * 512x512 bf16 = 4 MB
static constexpr long OFF_BBT  = OFF_PT  + 8L * 262144 * 2;    // 23,068,672
static constexpr long OFF_G    = OFF_BBT + 32768;              // 23,101,440 (16 x 512x32)
static constexpr long OFF_CA   = OFF_G   + 16L * 16384 * 2;    // 23,625,728 (17 x 64x512)
static constexpr long OFF_CG   = OFF_CA  + 17L * 32768 * 2;    // 24,739,840 (16 x 64x32)
// Xb overwrites PT/BbarT/G/CA/CG (all dead by k_packX time); ends 35,651,584
static constexpr long OFF_XB   = OFF_PT;

extern "C" void kernel_launch(void* const* d_in, const int* in_sizes, int n_in,
                              void* d_out, int out_size, void* d_ws, size_t ws_size,
                              hipStream_t stream){
  const float* z_dyn = (const float*)d_in[0];
  const float* dtp   = (const float*)d_in[2];
  const float* U     = (const float*)d_in[3];
  const float* skew  = (const float*)d_in[4];
  const float* gamma = (const float*)d_in[5];
  const float* B_ct  = (const float*)d_in[6];
  const float* Cin   = (const float*)d_in[7];
  const float* Din   = (const float*)d_in[8];
  float* Zout = (float*)d_out;
  float* Yout = Zout + 67108864L;   // 256*512*512

  char* ws = (char*)d_ws;
  float* Xf  = (float*)(ws + OFF_XF);
  float* X2f = (float*)(ws + OFF_X2F);
  float* X3f = (float*)(ws + OFF_X3F);
  float* B0f = (float*)(ws + OFF_B0F);
  float* Ff  = (float*)(ws + OFF_FF);
  unsigned short* XAp  = (unsigned short*)(ws + OFF_XAP);
  unsigned short* XBt  = (unsigned short*)(ws + OFF_XBT);
  unsigned short* X2Ap = (unsigned short*)(ws + OFF_X2AP);
  unsigned short* X2Bt = (unsigned short*)(ws + OFF_X2BT);
  unsigned short* X4Bt = (unsigned short*)(ws + OFF_X4BT);
  unsigned short* B1Ap = (unsigned short*)(ws + OFF_B1AP);
  unsigned short* EAp  = (unsigned short*)(ws + OFF_EAP);
  unsigned short* EBt  = (unsigned short*)(ws + OFF_EBT);
  unsigned short* FAp  = (unsigned short*)(ws + OFF_FAP);
  unsigned short* FBt  = (unsigned short*)(ws + OFF_FBT);
  unsigned short* WbigT = (unsigned short*)(ws + OFF_WBT);
  unsigned short* PT    = (unsigned short*)(ws + OFF_PT);
  unsigned short* BbarT = (unsigned short*)(ws + OFF_BBT);
  unsigned short* Gar   = (unsigned short*)(ws + OFF_G);
  unsigned short* CAb   = (unsigned short*)(ws + OFF_CA);
  unsigned short* CGb   = (unsigned short*)(ws + OFF_CG);
  unsigned short* Xb    = (unsigned short*)(ws + OFF_XB);

  // prefix-scan scratch inside d_out (dead before k_mmbig overwrites all)
  float* S32a = Zout;                                   // 16 x 512x512 f32
  float* S32b = Zout + 4194304;                         // 16 x 512x512 f32
  unsigned short* Sb  = (unsigned short*)Yout;          // 16 x 512x512 bf16
  unsigned short* T16 = Sb  + 4194304;                  // 512x512 bf16 (ld512)
  unsigned short* TM2 = T16 + 262144;
  unsigned short* TM4 = TM2 + 262144;
  unsigned short* M2b = TM4 + 262144;                   // 512x1024 bf16 (ld1024)
  unsigned short* M4b = M2b + 524288;
  unsigned short* M8b = M4b + 524288;

  dim3 b256(256);
  dim3 gE(18, 18);
  const long WBLK = 524288;  // 512*1024 elements
  const long PBLK = 262144;  // 512*512 elements

  // ---- expm(Maug*dt): scaling s=2 + degree-7 PS Taylor (6 GEMMs) ----
  k_build_M<<<dim3(1296), b256, 0, stream>>>(skew, gamma, dtp, B_ct, Xf, XAp, XBt);
  k_expm_gemm<<<gE, b256, 0, stream>>>(XAp,  XBt,  nullptr, X2f, X2Ap, X2Bt);      // X2
  k_expm_gemm<<<gE, b256, 0, stream>>>(X2Ap, XBt,  nullptr, X3f, nullptr, nullptr); // X3
  k_expm_gemm<<<gE, b256, 0, stream>>>(X2Ap, X2Bt, nullptr, nullptr, nullptr, X4Bt);// X4
  k_poly<<<dim3(1296), b256, 0, stream>>>(Xf, X2f, X3f, B0f, B1Ap);
  k_expm_gemm<<<gE, b256, 0, stream>>>(B1Ap, X4Bt, B0f, nullptr, EAp, EBt);        // E = B1*X4+B0
  k_expm_gemm<<<gE, b256, 0, stream>>>(EAp, EBt, nullptr, nullptr, FAp, FBt);      // F = E^2
  k_expm_gemm<<<gE, b256, 0, stream>>>(FAp, FBt, nullptr, Ff, nullptr, nullptr);   // Ff = F^2

  // ---- extract A_bar/B_bar, padded C ----
  k_extract<<<dim3(1024), b256, 0, stream>>>(Ff, Cin, WbigT, PT, BbarT, Gar, CAb);

  // ---- powers of A by doubling: Apow_j = WbigT block j-1 (ld 1024) ----
  k_btgemm<64,64,2,2><<<dim3(8,8,1), b256, 0, stream>>>(WbigT, 1024, 0, PT, 512, 0, WbigT + WBLK, 1024, 0, 512, nullptr, 0, 0);               // A2
  k_transpose512<<<dim3(1024,1,1), b256, 0, stream>>>(WbigT + WBLK, WBLK, PT + PBLK, PBLK);                                                    // PT2
  k_btgemm<64,64,2,2><<<dim3(8,8,2), b256, 0, stream>>>(WbigT + WBLK, 1024, 0, PT, 512, PBLK, WbigT + 2*WBLK, 1024, WBLK, 512, nullptr, 0, 0); // A3,4
  k_transpose512<<<dim3(1024,1,2), b256, 0, stream>>>(WbigT + 2*WBLK, WBLK, PT + 2*PBLK, PBLK);                                                // PT3,4
  k_btgemm<64,64,2,2><<<dim3(8,8,4), b256, 0, stream>>>(WbigT + 3*WBLK, 1024, 0, PT, 512, PBLK, WbigT + 4*WBLK, 1024, WBLK, 512, nullptr, 0, 0);// A5..8
  k_transpose512<<<dim3(1024,1,4), b256, 0, stream>>>(WbigT + 4*WBLK, WBLK, PT + 4*PBLK, PBLK);                                                // PT5..8
  k_btgemm<64,64,2,2><<<dim3(8,8,8), b256, 0, stream>>>(WbigT + 7*WBLK, 1024, 0, PT, 512, PBLK, WbigT + 8*WBLK, 1024, WBLK, 512, nullptr, 0, 0);// A9..16
  // G_k = Apow_k * B_bar (k=1..15); G_0 from extract
  k_btgemm<64,32,4,1><<<dim3(1,8,15), b256, 0, stream>>>(WbigT, 1024, WBLK, BbarT, 512, 0, Gar + 16384, 32, 16384, 512, nullptr, 0, 0);

  // ---- CA_m = C@A^m (m=1..16), CG_m = CA_m@B_bar (m=0..15) for Y fusion ----
  k_btgemm<64,64,2,2><<<dim3(8,1,8), b256, 0, stream>>>(CAb, 512, 0, PT, 512, PBLK, CAb + 32768, 512, 32768, 512, nullptr, 0, 0);              // CA1..8
  k_btgemm<64,64,2,2><<<dim3(8,1,8), b256, 0, stream>>>(CAb + 32768, 512, 32768, PT + 7*PBLK, 512, 0, CAb + 9L*32768, 512, 32768, 512, nullptr, 0, 0); // CA9..16
  k_btgemm<64,32,4,1><<<dim3(1,1,16), b256, 0, stream>>>(CAb, 512, 32768, BbarT, 512, 0, CGb, 32, 2048, 512, nullptr, 0, 0);                   // CG0..15

  // ---- assemble W (U-region + Y-region), pack X buffers ----
  k_assembleU<<<dim3(16384), b256, 0, stream>>>(Gar, WbigT);
  k_assembleWy<<<dim3(4096), b256, 0, stream>>>(CAb, CGb, Din, dtp, WbigT);
  k_packX<<<dim3(32768), b256, 0, stream>>>(z_dyn, U, Xb, S32a);

  // ---- prefix-scan power chain: M2=A16^2, M4, M8 (row-major, ld1024) ----
  unsigned short* Wlast = WbigT + 15L * WBLK;
  k_transpose512<<<dim3(1024,1,1), b256, 0, stream>>>(Wlast, 0, T16, 0);
  k_btgemm<64,64,2,2><<<dim3(8,8,1), b256, 0, stream>>>(Wlast, 1024, 0, T16, 512, 0, M2b, 1024, 0, 512, nullptr, 0, 0);
  k_transpose512<<<dim3(1024,1,1), b256, 0, stream>>>(M2b, 0, TM2, 0);
  k_btgemm<64,64,2,2><<<dim3(8,8,1), b256, 0, stream>>>(M2b, 1024, 0, TM2, 512, 0, M4b, 1024, 0, 512, nullptr, 0, 0);
  k_transpose512<<<dim3(1024,1,1), b256, 0, stream>>>(M4b, 0, TM4, 0);
  k_btgemm<64,64,2,2><<<dim3(8,8,1), b256, 0, stream>>>(M4b, 1024, 0, TM4, 512, 0, M8b, 1024, 0, 512, nullptr, 0, 0);

  // ---- Ubar_c = U_c @ GU^T -> init S[c+1] (bf16 into Xb z0-slots + f32) ----
  k_btgemm<64,64,2,2><<<dim3(8,8,15), b256, 0, stream>>>(
      Xb + 512, 1024, WBLK, Wlast + 512, 1024, 0,
      Xb + WBLK, 1024, WBLK, 512, S32a + PBLK, 512, PBLK);

  // ---- Hillis-Steele: 4 rounds, ping-pong (f32 carry, bf16 operand) ----
  k_scanround<<<dim3(8,8,16), b256, 0, stream>>>(Xb, 1024, WBLK, S32a, Wlast, 1024, S32b, Sb, 512, PBLK, 1);
  k_scanround<<<dim3(8,8,16), b256, 0, stream>>>(Sb, 512, PBLK, S32b, M2b, 1024, S32a, Xb, 1024, WBLK, 2);
  k_scanround<<<dim3(8,8,16), b256, 0, stream>>>(Xb, 1024, WBLK, S32a, M4b, 1024, S32b, Sb, 512, PBLK, 4);
  k_scanround<<<dim3(8,8,16), b256, 0, stream>>>(Sb, 512, PBLK, S32b, M8b, 1024, S32a, Xb, 1024, WBLK, 8);

  // ---- ONE parallel dispatch: all 16 chunks, Z (n<8192) + Y (n>=8192) ----
  k_mmbig<<<dim3(72, 4, 16), b256, 0, stream>>>(Xb, WbigT, Zout, Yout);
}

// Round 3
// 683.165 us; speedup vs baseline: 1.5438x; 1.1626x over previous
//
#include <hip/hip_runtime.h>
#include <stdint.h>

// ---------------------------------------------------------------------------
// ConditionedCTKoopmanTransition: d=512, u=32, n_obs=50, B=512, T=256
// v4:
//   1. All MFMA kernels: LDS XOR-swizzle (pre-swizzled global src, linear
//      global_load_lds dest, swizzled ds_read) + double-buffered counted
//      s_waitcnt vmcnt(N) pipeline (never drain to 0 mid-loop).
//   2. expm GEMMs BK=192 (9 k-iters instead of 27).
//   3. Transposes fused into k_btgemm (outT) — 6 dispatches deleted.
//   4. bf16-only Hillis-Steele scan (f32 carry dropped; 4 bf16 hops vs the
//      validated 15-hop all-bf16 serial version).
//   5. assembleU+Wy merged; prefix powers run before packX (Xb aliases PT).
// ---------------------------------------------------------------------------

typedef __bf16 bf16x8 __attribute__((ext_vector_type(8)));
typedef float  f32x4  __attribute__((ext_vector_type(4)));

#define NE  576
#define NE3 1728   // 3*NE (split-bf16: [hi|hi|lo] x [hi|lo|hi])

__device__ __forceinline__ unsigned short f2bf(float x){
  union { float f; unsigned int u; } v; v.f = x;
  unsigned int r = (v.u + 0x7fffu + ((v.u >> 16) & 1u)) >> 16;
  return (unsigned short)r;
}
__device__ __forceinline__ float bf2f(unsigned short h){
  union { float f; unsigned int u; } v; v.u = ((unsigned int)h) << 16;
  return v.f;
}

__device__ __forceinline__ void gll16(const void* g, void* l){
  __builtin_amdgcn_global_load_lds((__attribute__((address_space(1))) void*)g,
                                   (__attribute__((address_space(3))) void*)l,
                                   16, 0, 0);
}

// ---------------------------------------------------------------------------
// build scaled augmented matrix X = Maug * dt / 4, f32 + split forms
// ---------------------------------------------------------------------------
__global__ __launch_bounds__(256) void k_build_M(
    const float* __restrict__ skew, const float* __restrict__ gamma,
    const float* __restrict__ dtp, const float* __restrict__ B_ct,
    float* __restrict__ Xf, unsigned short* __restrict__ XAp,
    unsigned short* __restrict__ XBt){
  int id = blockIdx.x * 256 + threadIdx.x;
  if (id >= NE * NE) return;
  int r = id / NE, c = id % NE;
  float sc = dtp[0] * 0.25f;     // s=2 scaling
  float v = 0.f;
  if (r < 512 && c < 512) {
    if (r < c) {
      long k = 511L * r - (long)r * (r - 1) / 2 + (c - r - 1);
      v = skew[k];
    } else if (r > c) {
      long k = 511L * c - (long)c * (c - 1) / 2 + (r - c - 1);
      v = -skew[k];
    } else {
      float g = gamma[r];
      float sp = (g > 20.f) ? g : log1pf(expf(g));
      v = -sp;
    }
  } else if (r < 512 && c >= 512 && c < 544) {
    v = B_ct[r * 32 + (c - 512)];
  }
  v *= sc;
  Xf[id] = v;
  unsigned short hi = f2bf(v);
  unsigned short lo = f2bf(v - bf2f(hi));
  XAp[(long)r * NE3 + c]          = hi;
  XAp[(long)r * NE3 + NE + c]     = hi;
  XAp[(long)r * NE3 + 2 * NE + c] = lo;
  XBt[(long)c * NE3 + r]          = hi;
  XBt[(long)c * NE3 + NE + r]     = lo;
  XBt[(long)c * NE3 + 2 * NE + r] = hi;
}

// ---------------------------------------------------------------------------
// split-bf16 GEMM for expm: C(576x576) = A*B (+Cadd), K=1728, BK=192,
// dbuf + swizzle + counted vmcnt.
// ---------------------------------------------------------------------------
__global__ __launch_bounds__(256) void k_expm_gemm(
    const unsigned short* __restrict__ Ap, const unsigned short* __restrict__ Bt,
    const float* __restrict__ Cadd, float* __restrict__ outF,
    unsigned short* __restrict__ outAp, unsigned short* __restrict__ outBt){
  __shared__ __align__(16) unsigned short As[2][32 * 192];
  __shared__ __align__(16) unsigned short Bs[2][32 * 192];
  int tid = threadIdx.x, wave = tid >> 6, lane = tid & 63;
  int wm = wave & 1, wn = wave >> 1;
  int m0 = blockIdx.y * 32, n0 = blockIdx.x * 32;
  int lr = lane & 15, kq = lane >> 4;
  f32x4 acc = {0.f, 0.f, 0.f, 0.f};
  auto stage = [&](int buf, int kt){
    #pragma unroll
    for (int i = 0; i < 3; i++) {
      int base = i * 256 + wave * 64;     // wave-uniform LDS base
      int cc = base + lane;
      int rr = cc / 24, sl = cc - rr * 24;
      int ss = (sl & 24) | ((sl & 7) ^ (rr & 7));
      gll16(Ap + (long)(m0 + rr) * NE3 + kt + ss * 8, &As[buf][base * 8]);
      gll16(Bt + (long)(n0 + rr) * NE3 + kt + ss * 8, &Bs[buf][base * 8]);
    }
  };
  stage(0, 0);
  int cur = 0;
  for (int kt = 0; kt < NE3; kt += 192) {
    if (kt + 192 < NE3) {
      stage(cur ^ 1, kt + 192);
      asm volatile("s_waitcnt vmcnt(6)" ::: "memory");
    } else {
      asm volatile("s_waitcnt vmcnt(0)" ::: "memory");
    }
    __builtin_amdgcn_s_barrier();
    __builtin_amdgcn_sched_barrier(0);
    #pragma unroll
    for (int hh = 0; hh < 6; hh++) {
      int eo = (hh * 32 + kq * 8) ^ ((lr & 7) << 3);
      bf16x8 af = *(const bf16x8*)&As[cur][(wm * 16 + lr) * 192 + eo];
      bf16x8 bf = *(const bf16x8*)&Bs[cur][(wn * 16 + lr) * 192 + eo];
      acc = __builtin_amdgcn_mfma_f32_16x16x32_bf16(af, bf, acc, 0, 0, 0);
    }
    __builtin_amdgcn_s_barrier();
    cur ^= 1;
  }
  int n = n0 + wn * 16 + lr;
  for (int i = 0; i < 4; i++) {
    int m = m0 + wm * 16 + kq * 4 + i;
    float v = acc[i];
    if (Cadd) v += Cadd[(long)m * NE + n];
    if (outF) outF[(long)m * NE + n] = v;
    unsigned short hi = f2bf(v);
    unsigned short lo = f2bf(v - bf2f(hi));
    if (outAp) {
      outAp[(long)m * NE3 + n]          = hi;
      outAp[(long)m * NE3 + NE + n]     = hi;
      outAp[(long)m * NE3 + 2 * NE + n] = lo;
    }
    if (outBt) {
      outBt[(long)n * NE3 + m]          = hi;
      outBt[(long)n * NE3 + NE + m]     = lo;
      outBt[(long)n * NE3 + 2 * NE + m] = hi;
    }
  }
}

// ---------------------------------------------------------------------------
// degree-7 PS coefficients: B0 (f32 Cadd), B1 (split Ap).  E = B1*X4 + B0
// ---------------------------------------------------------------------------
__global__ __launch_bounds__(256) void k_poly(
    const float* __restrict__ Xf, const float* __restrict__ X2f,
    const float* __restrict__ X3f, float* __restrict__ B0,
    unsigned short* __restrict__ B1Ap){
  int id = blockIdx.x * 256 + threadIdx.x;
  if (id >= NE * NE) return;
  int r = id / NE, c = id % NE;
  float x = Xf[id], x2 = X2f[id], x3 = X3f[id];
  float ii = (r == c) ? 1.f : 0.f;
  float b0 = ii + x + x2 * 0.5f + x3 * (1.f / 6.f);
  float b1 = ii * (1.f / 24.f) + x * (1.f / 120.f) + x2 * (1.f / 720.f) + x3 * (1.f / 5040.f);
  B0[id] = b0;
  unsigned short hi = f2bf(b1), lo = f2bf(b1 - bf2f(hi));
  B1Ap[(long)r * NE3 + c]          = hi;
  B1Ap[(long)r * NE3 + NE + c]     = hi;
  B1Ap[(long)r * NE3 + 2 * NE + c] = lo;
}

// ---------------------------------------------------------------------------
// extract A_bar/B_bar from expm result; padded C (64 rows) as CA block 0
// ---------------------------------------------------------------------------
__global__ __launch_bounds__(256) void k_extract(
    const float* __restrict__ F, const float* __restrict__ Cin,
    unsigned short* __restrict__ WbigT, unsigned short* __restrict__ PT1,
    unsigned short* __restrict__ BbarT, unsigned short* __restrict__ G0,
    unsigned short* __restrict__ CA0){
  long id = (long)blockIdx.x * 256 + threadIdx.x;
  if (id < 512 * 512) {
    int m = (int)(id >> 9), k = (int)(id & 511);
    WbigT[(long)m * 1024 + k] = f2bf(F[(long)m * NE + k]);   // A^1 row-major
    PT1[id] = f2bf(F[(long)k * NE + m]);                      // (A^1)^T
  }
  if (id < 512 * 32) {
    int dd = (int)(id >> 5), u = (int)(id & 31);
    unsigned short h = f2bf(F[(long)dd * NE + 512 + u]);
    G0[id] = h;                         // B_bar row-major (512x32)
    BbarT[(long)u * 512 + dd] = h;      // B_bar^T (32x512)
  }
  if (id < 64 * 512) {                  // zero-padded C (rows 50..63 = 0)
    CA0[id] = (id < 50 * 512) ? f2bf(Cin[id]) : (unsigned short)0;
  }
}

// ---------------------------------------------------------------------------
// generic bf16 "bt" GEMM, BK=64, dbuf+swizzle+counted vmcnt:
//   C[m,n] = sum_k A[m,k]*Bt[n,k]; optional transpose output outT = C^T.
// ---------------------------------------------------------------------------
template<int BM, int BN, int WM, int WN>
__global__ __launch_bounds__(256) void k_btgemm(
    const unsigned short* __restrict__ A, int ldA, long sAz,
    const unsigned short* __restrict__ Bt, int ldB, long sBz,
    unsigned short* __restrict__ C, int ldC, long sCz, int K,
    unsigned short* __restrict__ outT, int ldT, long sTz){
  constexpr int FM = BM / (16 * WM), FN = BN / (16 * WN);
  constexpr int LA = BM / 32, LB = BN / 32;
  __shared__ __align__(16) unsigned short As[2][BM * 64];
  __shared__ __align__(16) unsigned short Bs[2][BN * 64];
  int tid = threadIdx.x, wave = tid >> 6, lane = tid & 63;
  int wm = wave % WM, wn = wave / WM;
  long z = blockIdx.z;
  const unsigned short* Ab = A + z * sAz;
  const unsigned short* Bb = Bt + z * sBz;
  int m0 = blockIdx.y * BM, n0 = blockIdx.x * BN;
  int lr = lane & 15, kq = lane >> 4;
  f32x4 acc[FM][FN];
  f32x4 z4 = {0.f, 0.f, 0.f, 0.f};
  for (int i = 0; i < FM; i++) for (int j = 0; j < FN; j++) acc[i][j] = z4;
  auto stage = [&](int buf, int kt){
    #pragma unroll
    for (int i = 0; i < LA; i++) {
      int base = i * 256 + wave * 64;
      int cc = base + lane; int rr = cc >> 3, sl = cc & 7;
      gll16(Ab + (long)(m0 + rr) * ldA + kt + ((sl ^ (rr & 7)) << 3), &As[buf][base * 8]);
    }
    #pragma unroll
    for (int i = 0; i < LB; i++) {
      int base = i * 256 + wave * 64;
      int cc = base + lane; int rr = cc >> 3, sl = cc & 7;
      gll16(Bb + (long)(n0 + rr) * ldB + kt + ((sl ^ (rr & 7)) << 3), &Bs[buf][base * 8]);
    }
  };
  stage(0, 0);
  int cur = 0;
  for (int kt = 0; kt < K; kt += 64) {
    if (kt + 64 < K) {
      stage(cur ^ 1, kt + 64);
      asm volatile("s_waitcnt vmcnt(%0)" :: "i"(LA + LB) : "memory");
    } else {
      asm volatile("s_waitcnt vmcnt(0)" ::: "memory");
    }
    __builtin_amdgcn_s_barrier();
    __builtin_amdgcn_sched_barrier(0);
    #pragma unroll
    for (int h = 0; h < 2; h++) {
      int eo = (h * 32 + kq * 8) ^ ((lr & 7) << 3);
      bf16x8 af[FM], bfr[FN];
      #pragma unroll
      for (int i = 0; i < FM; i++)
        af[i] = *(const bf16x8*)&As[cur][(wm * (16 * FM) + i * 16 + lr) * 64 + eo];
      #pragma unroll
      for (int j = 0; j < FN; j++)
        bfr[j] = *(const bf16x8*)&Bs[cur][(wn * (16 * FN) + j * 16 + lr) * 64 + eo];
      #pragma unroll
      for (int i = 0; i < FM; i++)
        #pragma unroll
        for (int j = 0; j < FN; j++)
          acc[i][j] = __builtin_amdgcn_mfma_f32_16x16x32_bf16(af[i], bfr[j], acc[i][j], 0, 0, 0);
    }
    __builtin_amdgcn_s_barrier();
    cur ^= 1;
  }
  unsigned short* Cb = C + z * sCz;
  unsigned short* Tb = outT ? outT + z * sTz : nullptr;
  for (int i = 0; i < FM; i++)
    for (int j = 0; j < FN; j++) {
      int n = n0 + wn * (16 * FN) + j * 16 + lr;
      for (int r = 0; r < 4; r++) {
        int m = m0 + wm * (16 * FM) + i * 16 + kq * 4 + r;
        unsigned short hv = f2bf(acc[i][j][r]);
        Cb[(long)m * ldC + n] = hv;
        if (Tb) Tb[(long)n * ldT + m] = hv;
      }
    }
}

// ---------------------------------------------------------------------------
// merged: fill U-region (rows 0..8191) and Y-region (rows 8192..9215) of W
// ---------------------------------------------------------------------------
__global__ __launch_bounds__(256) void k_assembleUW(
    const unsigned short* __restrict__ G, const unsigned short* __restrict__ CA,
    const unsigned short* __restrict__ CG, const float* __restrict__ Din,
    const float* __restrict__ dtp, unsigned short* __restrict__ WbigT){
  long id = (long)blockIdx.x * 256 + threadIdx.x;
  if (id < 4194304) {              // U-region: 8192*512
    int n = (int)(id >> 9), kk2 = (int)(id & 511);
    int j = (n >> 9) + 1, dcol = n & 511;
    int i = (kk2 >> 5) + 1, uu = kk2 & 31;
    unsigned short v = 0;
    if (i <= j) v = G[(long)(j - i) * 16384 + dcol * 32 + uu];
    WbigT[(long)n * 1024 + 512 + kk2] = v;
  } else {                          // Y-region: 1024*1024
    int id2 = (int)(id - 4194304);
    int np = id2 >> 10, kp = id2 & 1023;
    int jm1 = np >> 6, o = np & 63;
    unsigned short v;
    if (kp < 512) {
      v = CA[(long)(jm1 + 1) * 32768 + o * 512 + kp];
    } else {
      int i = ((kp - 512) >> 5) + 1, u = kp & 31;
      float f = 0.f;
      if (i <= jm1 + 1) f = bf2f(CG[(long)(jm1 + 1 - i) * 2048 + o * 32 + u]);
      if (i == jm1 + 1 && o < 50) f += dtp[0] * Din[o * 32 + u];
      v = f2bf(f);
    }
    WbigT[(long)(8192 + np) * 1024 + kp] = v;
  }
}

// pack Xbuf: [Z0 bf16 (c=0 only) | U bf16 for all chunks]
__global__ __launch_bounds__(256) void k_packX(
    const float* __restrict__ zdyn, const float* __restrict__ U,
    unsigned short* __restrict__ Xbuf){
  long id = (long)blockIdx.x * 256 + threadIdx.x;   // over 16*512*1024
  long c = id >> 19;
  int rem = (int)(id & ((1 << 19) - 1));
  int b = rem >> 10, col = rem & 1023;
  if (col < 512) {
    if (c == 0) Xbuf[id] = f2bf(zdyn[(long)b * 512 + col]);
  } else {
    int kk2 = col - 512;
    int t = (int)(c * 16) + (kk2 >> 5), uu = kk2 & 31;
    Xbuf[id] = f2bf(U[((long)t * 512 + b) * 32 + uu]);
  }
}

// ---------------------------------------------------------------------------
// Hillis-Steele prefix round (bf16 state): out[c] = in[c] + in[c-h]@R^T
// (pass-through for c<h).  64x64 tiles, dbuf+swizzle+counted vmcnt.
// ---------------------------------------------------------------------------
__global__ __launch_bounds__(256) void k_scanround(
    const unsigned short* __restrict__ Sin, int ldS, long sS,
    const unsigned short* __restrict__ R, int ldR,
    unsigned short* __restrict__ Out, int ldO, long sO, int h){
  __shared__ __align__(16) unsigned short As[2][64 * 64];
  __shared__ __align__(16) unsigned short Bs[2][64 * 64];
  int tid = threadIdx.x, wave = tid >> 6, lane = tid & 63;
  int wm = wave & 1, wn = wave >> 1;
  int c = blockIdx.z;
  int m0 = blockIdx.y * 64, n0 = blockIdx.x * 64;
  int lr = lane & 15, kq = lane >> 4;
  f32x4 acc[2][2];
  f32x4 z4 = {0.f, 0.f, 0.f, 0.f};
  for (int i = 0; i < 2; i++) for (int j = 0; j < 2; j++) acc[i][j] = z4;
  if (c >= h) {
    const unsigned short* Ab = Sin + (long)(c - h) * sS;
    auto stage = [&](int buf, int kt){
      #pragma unroll
      for (int i = 0; i < 2; i++) {
        int base = i * 256 + wave * 64;
        int cc = base + lane; int rr = cc >> 3, sl = cc & 7;
        gll16(Ab + (long)(m0 + rr) * ldS + kt + ((sl ^ (rr & 7)) << 3), &As[buf][base * 8]);
      }
      #pragma unroll
      for (int i = 0; i < 2; i++) {
        int base = i * 256 + wave * 64;
        int cc = base + lane; int rr = cc >> 3, sl = cc & 7;
        gll16(R + (long)(n0 + rr) * ldR + kt + ((sl ^ (rr & 7)) << 3), &Bs[buf][base * 8]);
      }
    };
    stage(0, 0);
    int cur = 0;
    for (int kt = 0; kt < 512; kt += 64) {
      if (kt + 64 < 512) {
        stage(cur ^ 1, kt + 64);
        asm volatile("s_waitcnt vmcnt(4)" ::: "memory");
      } else {
        asm volatile("s_waitcnt vmcnt(0)" ::: "memory");
      }
      __builtin_amdgcn_s_barrier();
      __builtin_amdgcn_sched_barrier(0);
      #pragma unroll
      for (int h2 = 0; h2 < 2; h2++) {
        int eo = (h2 * 32 + kq * 8) ^ ((lr & 7) << 3);
        bf16x8 af[2], bfr[2];
        #pragma unroll
        for (int i = 0; i < 2; i++)
          af[i] = *(const bf16x8*)&As[cur][(wm * 32 + i * 16 + lr) * 64 + eo];
        #pragma unroll
        for (int j = 0; j < 2; j++)
          bfr[j] = *(const bf16x8*)&Bs[cur][(wn * 32 + j * 16 + lr) * 64 + eo];
        #pragma unroll
        for (int i = 0; i < 2; i++)
          #pragma unroll
          for (int j = 0; j < 2; j++)
            acc[i][j] = __builtin_amdgcn_mfma_f32_16x16x32_bf16(af[i], bfr[j], acc[i][j], 0, 0, 0);
      }
      __builtin_amdgcn_s_barrier();
      cur ^= 1;
    }
  }
  const unsigned short* inC = Sin + (long)c * sS;
  unsigned short* OB = Out + (long)c * sO;
  for (int j = 0; j < 2; j++) {
    int n = n0 + wn * 32 + j * 16 + lr;
    for (int i = 0; i < 2; i++)
      for (int r = 0; r < 4; r++) {
        int m = m0 + wm * 32 + i * 16 + kq * 4 + r;
        float v = acc[i][j][r] + bf2f(inC[(long)m * ldS + n]);
        OB[(long)m * ldO + n] = f2bf(v);
      }
  }
}

// ---------------------------------------------------------------------------
// big fused GEMM: all 16 chunks, [z0_c|U_c](512x1024) @ W^T(1024x9216)
//  n<8192 -> Z f32; n>=8192 -> Y f32 (o<50).  BK=64, dbuf+swizzle+vmcnt.
// ---------------------------------------------------------------------------
__global__ __launch_bounds__(256) void k_mmbig(
    const unsigned short* __restrict__ Xall, const unsigned short* __restrict__ W,
    float* __restrict__ Zout, float* __restrict__ Yout){
  __shared__ __align__(16) unsigned short As[2][128 * 64];
  __shared__ __align__(16) unsigned short Bs[2][128 * 64];
  int tid = threadIdx.x, wave = tid >> 6, lane = tid & 63;
  int wm = wave & 1, wn = wave >> 1;
  int c = blockIdx.z;
  const unsigned short* Xc = Xall + (long)c * 524288;
  int m0 = blockIdx.y * 128, n0 = blockIdx.x * 128;
  int lr = lane & 15, kq = lane >> 4;
  f32x4 acc[4][4];
  f32x4 z4 = {0.f, 0.f, 0.f, 0.f};
  for (int i = 0; i < 4; i++) for (int j = 0; j < 4; j++) acc[i][j] = z4;
  auto stage = [&](int buf, int kt){
    #pragma unroll
    for (int i = 0; i < 4; i++) {
      int base = i * 256 + wave * 64;
      int cc = base + lane; int rr = cc >> 3, sl = cc & 7;
      gll16(Xc + (long)(m0 + rr) * 1024 + kt + ((sl ^ (rr & 7)) << 3), &As[buf][base * 8]);
    }
    #pragma unroll
    for (int i = 0; i < 4; i++) {
      int base = i * 256 + wave * 64;
      int cc = base + lane; int rr = cc >> 3, sl = cc & 7;
      gll16(W + (long)(n0 + rr) * 1024 + kt + ((sl ^ (rr & 7)) << 3), &Bs[buf][base * 8]);
    }
  };
  stage(0, 0);
  int cur = 0;
  for (int kt = 0; kt < 1024; kt += 64) {
    if (kt + 64 < 1024) {
      stage(cur ^ 1, kt + 64);
      asm volatile("s_waitcnt vmcnt(8)" ::: "memory");
    } else {
      asm volatile("s_waitcnt vmcnt(0)" ::: "memory");
    }
    __builtin_amdgcn_s_barrier();
    __builtin_amdgcn_sched_barrier(0);
    #pragma unroll
    for (int h = 0; h < 2; h++) {
      int eo = (h * 32 + kq * 8) ^ ((lr & 7) << 3);
      bf16x8 af[4], bfr[4];
      #pragma unroll
      for (int i = 0; i < 4; i++)
        af[i] = *(const bf16x8*)&As[cur][(wm * 64 + i * 16 + lr) * 64 + eo];
      #pragma unroll
      for (int j = 0; j < 4; j++)
        bfr[j] = *(const bf16x8*)&Bs[cur][(wn * 64 + j * 16 + lr) * 64 + eo];
      #pragma unroll
      for (int i = 0; i < 4; i++)
        #pragma unroll
        for (int j = 0; j < 4; j++)
          acc[i][j] = __builtin_amdgcn_mfma_f32_16x16x32_bf16(af[i], bfr[j], acc[i][j], 0, 0, 0);
    }
    __builtin_amdgcn_s_barrier();
    cur ^= 1;
  }
  int t0 = c * 16;
  if (n0 < 8192) {
    int jm1 = n0 >> 9;              // block never crosses a 512 boundary
    float* Zt = Zout + (long)(t0 + jm1) * 262144;
    for (int j = 0; j < 4; j++) {
      int n = n0 + wn * 64 + j * 16 + lr, dcol = n & 511;
      for (int i = 0; i < 4; i++)
        for (int r = 0; r < 4; r++) {
          int m = m0 + wm * 64 + i * 16 + kq * 4 + r;
          Zt[(long)m * 512 + dcol] = acc[i][j][r];
        }
    }
  } else {
    for (int j = 0; j < 4; j++) {
      int n = n0 + wn * 64 + j * 16 + lr;
      int q = n - 8192, jm1 = q >> 6, o = q & 63;
      if (o >= 50) continue;
      int t = t0 + jm1;
      for (int i = 0; i < 4; i++)
        for (int r = 0; r < 4; r++) {
          int m = m0 + wm * 64 + i * 16 + kq * 4 + r;
          Yout[((long)t * 512 + m) * 50 + o] = acc[i][j][r];
        }
    }
  }
}

// ---------------------------------------------------------------------------
// workspace layout (bytes)
// ---------------------------------------------------------------------------
static constexpr long NE2F = 331776L * 4;   // 576^2 f32      = 1,327,104
static constexpr long SPLT = 995328L * 2;   // 576*1728 bf16  = 1,990,656
// region A (expm scratch; only FF is read after the expm chain)
static constexpr long OFF_XF   = 0;
static constexpr long OFF_X2F  = OFF_XF   + NE2F;
static constexpr long OFF_X3F  = OFF_X2F  + NE2F;
static constexpr long OFF_B0F  = OFF_X3F  + NE2F;
static constexpr long OFF_XAP  = OFF_B0F  + NE2F;
static constexpr long OFF_XBT  = OFF_XAP  + SPLT;
static constexpr long OFF_X2AP = OFF_XBT  + SPLT;
static constexpr long OFF_X2BT = OFF_X2AP + SPLT;
static constexpr long OFF_X4BT = OFF_X2BT + SPLT;
static constexpr long OFF_B1AP = OFF_X4BT + SPLT;
static constexpr long OFF_EAP  = OFF_B1AP + SPLT;
static constexpr long OFF_EBT  = OFF_EAP  + SPLT;
static constexpr long OFF_FAP  = OFF_EBT  + SPLT;
static constexpr long OFF_FBT  = OFF_FAP  + SPLT;
static constexpr long OFF_FF   = OFF_FBT  + SPLT;     // 25.21M .. 26.54M
// region B aliases region A (all region-A buffers dead when overwritten)
static constexpr long OFF_WBT  = 0;                            // 9216x1024 bf16
static constexpr long OFF_PT   = 18874368;                     // 16 x 512x512 bf16 = 8 MB
static constexpr long OFF_BBT  = OFF_PT  + 16L * 262144 * 2;   // 27,262,976
static constexpr long OFF_G    = OFF_BBT + 32768;              // (16 x 512x32)
static constexpr long OFF_CA   = OFF_G   + 16L * 16384 * 2;    // (17 x 64x512)
static constexpr long OFF_CG   = OFF_CA  + 17L * 32768 * 2;    // (16 x 64x32)
// Xb overwrites PT/BbarT/G/CA/CG (all dead by k_packX time); ends 35,651,584
static constexpr long OFF_XB   = OFF_PT;

extern "C" void kernel_launch(void* const* d_in, const int* in_sizes, int n_in,
                              void* d_out, int out_size, void* d_ws, size_t ws_size,
                              hipStream_t stream){
  const float* z_dyn = (const float*)d_in[0];
  const float* dtp   = (const float*)d_in[2];
  const float* U     = (const float*)d_in[3];
  const float* skew  = (const float*)d_in[4];
  const float* gamma = (const float*)d_in[5];
  const float* B_ct  = (const float*)d_in[6];
  const float* Cin   = (const float*)d_in[7];
  const float* Din   = (const float*)d_in[8];
  float* Zout = (float*)d_out;
  float* Yout = Zout + 67108864L;   // 256*512*512

  char* ws = (char*)d_ws;
  float* Xf  = (float*)(ws + OFF_XF);
  float* X2f = (float*)(ws + OFF_X2F);
  float* X3f = (float*)(ws + OFF_X3F);
  float* B0f = (float*)(ws + OFF_B0F);
  float* Ff  = (float*)(ws + OFF_FF);
  unsigned short* XAp  = (unsigned short*)(ws + OFF_XAP);
  unsigned short* XBt  = (unsigned short*)(ws + OFF_XBT);
  unsigned short* X2Ap = (unsigned short*)(ws + OFF_X2AP);
  unsigned short* X2Bt = (unsigned short*)(ws + OFF_X2BT);
  unsigned short* X4Bt = (unsigned short*)(ws + OFF_X4BT);
  unsigned short* B1Ap = (unsigned short*)(ws + OFF_B1AP);
  unsigned short* EAp  = (unsigned short*)(ws + OFF_EAP);
  unsigned short* EBt  = (unsigned short*)(ws + OFF_EBT);
  unsigned short* FAp  = (unsigned short*)(ws + OFF_FAP);
  unsigned short* FBt  = (unsigned short*)(ws + OFF_FBT);
  unsigned short* WbigT = (unsigned short*)(ws + OFF_WBT);
  unsigned short* PT    = (unsigned short*)(ws + OFF_PT);
  unsigned short* BbarT = (unsigned short*)(ws + OFF_BBT);
  unsigned short* Gar   = (unsigned short*)(ws + OFF_G);
  unsigned short* CAb   = (unsigned short*)(ws + OFF_CA);
  unsigned short* CGb   = (unsigned short*)(ws + OFF_CG);
  unsigned short* Xb    = (unsigned short*)(ws + OFF_XB);

  // scratch inside d_out (dead before k_mmbig overwrites all of Z and Y)
  unsigned short* Sb  = (unsigned short*)Yout;   // 16 x 512x512 bf16 (ld512)
  unsigned short* M2b = Sb  + 4194304;           // A^32 row-major (ld512)
  unsigned short* TM2 = M2b + 262144;
  unsigned short* M4b = TM2 + 262144;
  unsigned short* TM4 = M4b + 262144;
  unsigned short* M8b = TM4 + 262144;

  dim3 b256(256);
  dim3 gE(18, 18);
  const long WBLK = 524288;  // 512*1024 elements
  const long PBLK = 262144;  // 512*512 elements
  unsigned short* Wlast = WbigT + 15L * WBLK;

  // ---- expm(Maug*dt): scaling s=2 + degree-7 PS Taylor (6 GEMMs) ----
  k_build_M<<<dim3(1296), b256, 0, stream>>>(skew, gamma, dtp, B_ct, Xf, XAp, XBt);
  k_expm_gemm<<<gE, b256, 0, stream>>>(XAp,  XBt,  nullptr, X2f, X2Ap, X2Bt);      // X2
  k_expm_gemm<<<gE, b256, 0, stream>>>(X2Ap, XBt,  nullptr, X3f, nullptr, nullptr); // X3
  k_expm_gemm<<<gE, b256, 0, stream>>>(X2Ap, X2Bt, nullptr, nullptr, nullptr, X4Bt);// X4
  k_poly<<<dim3(1296), b256, 0, stream>>>(Xf, X2f, X3f, B0f, B1Ap);
  k_expm_gemm<<<gE, b256, 0, stream>>>(B1Ap, X4Bt, B0f, nullptr, EAp, EBt);        // E = B1*X4+B0
  k_expm_gemm<<<gE, b256, 0, stream>>>(EAp, EBt, nullptr, nullptr, FAp, FBt);      // F = E^2
  k_expm_gemm<<<gE, b256, 0, stream>>>(FAp, FBt, nullptr, Ff, nullptr, nullptr);   // Ff = F^2

  // ---- extract A_bar/B_bar, padded C ----
  k_extract<<<dim3(1024), b256, 0, stream>>>(Ff, Cin, WbigT, PT, BbarT, Gar, CAb);

  // ---- powers of A by doubling (transpose fused via outT -> PT blocks) ----
  k_btgemm<64,64,2,2><<<dim3(8,8,1), b256, 0, stream>>>(WbigT, 1024, 0, PT, 512, 0, WbigT + WBLK, 1024, 0, 512, PT + PBLK, 512, 0);                    // A2 (+PT2)
  k_btgemm<64,64,2,2><<<dim3(8,8,2), b256, 0, stream>>>(WbigT + WBLK, 1024, 0, PT, 512, PBLK, WbigT + 2*WBLK, 1024, WBLK, 512, PT + 2*PBLK, 512, PBLK); // A3,4 (+PT3,4)
  k_btgemm<64,64,2,2><<<dim3(8,8,4), b256, 0, stream>>>(WbigT + 3*WBLK, 1024, 0, PT, 512, PBLK, WbigT + 4*WBLK, 1024, WBLK, 512, PT + 4*PBLK, 512, PBLK);// A5..8 (+PT5..8)
  k_btgemm<64,64,2,2><<<dim3(8,8,8), b256, 0, stream>>>(WbigT + 7*WBLK, 1024, 0, PT, 512, PBLK, WbigT + 8*WBLK, 1024, WBLK, 512, PT + 8*PBLK, 512, PBLK);// A9..16 (+PT9..16)

  // ---- prefix-scan powers A^32/A^64/A^128 (before packX overwrites PT) ----
  k_btgemm<64,64,2,2><<<dim3(8,8,1), b256, 0, stream>>>(Wlast, 1024, 0, PT + 15*PBLK, 512, 0, M2b, 512, 0, 512, TM2, 512, 0);
  k_btgemm<64,64,2,2><<<dim3(8,8,1), b256, 0, stream>>>(M2b, 512, 0, TM2, 512, 0, M4b, 512, 0, 512, TM4, 512, 0);
  k_btgemm<64,64,2,2><<<dim3(8,8,1), b256, 0, stream>>>(M4b, 512, 0, TM4, 512, 0, M8b, 512, 0, 512, nullptr, 0, 0);

  // ---- G_k = A^k * B_bar (k=1..15); CA_m = C@A^m; CG_m = CA_m@B_bar ----
  k_btgemm<64,32,4,1><<<dim3(1,8,15), b256, 0, stream>>>(WbigT, 1024, WBLK, BbarT, 512, 0, Gar + 16384, 32, 16384, 512, nullptr, 0, 0);
  k_btgemm<64,64,2,2><<<dim3(8,1,8), b256, 0, stream>>>(CAb, 512, 0, PT, 512, PBLK, CAb + 32768, 512, 32768, 512, nullptr, 0, 0);                    // CA1..8
  k_btgemm<64,64,2,2><<<dim3(8,1,8), b256, 0, stream>>>(CAb + 32768, 512, 32768, PT + 7*PBLK, 512, 0, CAb + 9L*32768, 512, 32768, 512, nullptr, 0, 0); // CA9..16
  k_btgemm<64,32,4,1><<<dim3(1,1,16), b256, 0, stream>>>(CAb, 512, 32768, BbarT, 512, 0, CGb, 32, 2048, 512, nullptr, 0, 0);                         // CG0..15

  // ---- assemble W (U+Y regions), pack X (overwrites PT..CG with Xb) ----
  k_assembleUW<<<dim3(20480), b256, 0, stream>>>(Gar, CAb, CGb, Din, dtp, WbigT);
  k_packX<<<dim3(32768), b256, 0, stream>>>(z_dyn, U, Xb);

  // ---- Ubar_c = U_c @ GU^T -> init S[c+1] (bf16 into Xb z0-slots) ----
  k_btgemm<64,64,2,2><<<dim3(8,8,15), b256, 0, stream>>>(
      Xb + 512, 1024, WBLK, Wlast + 512, 1024, 0,
      Xb + WBLK, 1024, WBLK, 512, nullptr, 0, 0);

  // ---- Hillis-Steele: 4 rounds, bf16 ping-pong ----
  k_scanround<<<dim3(8,8,16), b256, 0, stream>>>(Xb, 1024, WBLK, Wlast, 1024, Sb, 512, PBLK, 1);
  k_scanround<<<dim3(8,8,16), b256, 0, stream>>>(Sb, 512, PBLK, M2b, 512, Xb, 1024, WBLK, 2);
  k_scanround<<<dim3(8,8,16), b256, 0, stream>>>(Xb, 1024, WBLK, M4b, 512, Sb, 512, PBLK, 4);
  k_scanround<<<dim3(8,8,16), b256, 0, stream>>>(Sb, 512, PBLK, M8b, 512, Xb, 1024, WBLK, 8);

  // ---- ONE parallel dispatch: all 16 chunks, Z (n<8192) + Y (n>=8192) ----
  k_mmbig<<<dim3(72, 4, 16), b256, 0, stream>>>(Xb, WbigT, Zout, Yout);
}